// Round 7
// baseline (391.364 us; speedup 1.0000x reference)
//
#include <hip/hip_runtime.h>
#include <hip/hip_bf16.h>

// Problem dims (fixed by reference)
//   B=128, T=256, D_MODEL=128, D_INNER=256, D_STATE=16, D_CONV=4, DT_RANK=8
// I/O dtype: float32. MFMA bf16 for in/out_proj. R7: scan parallelized
// 8x via chunked linear-recurrence decomposition (scanA: local scans ->
// P,E; scanB: serial chunk combine -> Hin; scanC: exact re-scan with Hin).
// Outputs: h (128,128,128) then x_skip (128,256,128), fp32, concatenated.

typedef __attribute__((ext_vector_type(8))) short bf16x8;
typedef __attribute__((ext_vector_type(4))) short bf16x4;
typedef __attribute__((ext_vector_type(4))) float f32x4;
using bf16 = __hip_bfloat16;

static __device__ __forceinline__ short f2s(float v) {
  union { bf16 b; short s; } u; u.b = (bf16)v; return u.s;
}
static __device__ __forceinline__ float s2f(short s) {
  union { short s; bf16 b; } u; u.s = s; return (float)u.b;
}

// ---------------------------------------------------------------------------
// fp32 -> bf16 convert for x (4,194,304 elems), 4/thread.
// ---------------------------------------------------------------------------
__global__ __launch_bounds__(256) void cvt_x(const float* __restrict__ x,
                                             short* __restrict__ xb) {
  int i = (blockIdx.x * 256 + threadIdx.x) * 4;
  f32x4 v = *(const f32x4*)(x + i);
  bf16x4 o;
  o[0] = f2s(v[0]); o[1] = f2s(v[1]); o[2] = f2s(v[2]); o[3] = f2s(v[3]);
  *(bf16x4*)(xb + i) = o;
}

// ---------------------------------------------------------------------------
// Weight prep: ipw(512x128)->bf16, opw(128x256)->bf16,
// down_w (co,ci,k) -> WT[(k*128+ci)*128+co] fp32 (staged in d_out spare).
// ---------------------------------------------------------------------------
__global__ __launch_bounds__(256) void prep_w(const float* __restrict__ ipw,
                                              const float* __restrict__ opw,
                                              const float* __restrict__ dw,
                                              short* __restrict__ ipwb,
                                              short* __restrict__ opwb,
                                              float* __restrict__ wt) {
  int idx = blockIdx.x * 256 + threadIdx.x;   // 0 .. 147455
  if (idx < 65536) {
    ipwb[idx] = f2s(ipw[idx]);
  } else if (idx < 98304) {
    int j = idx - 65536;
    opwb[j] = f2s(opw[j]);
  } else {
    int j = idx - 98304;          // (k*128+ci)*128 + co
    int co = j & 127;
    int p  = j >> 7;              // k*128+ci
    int k  = p >> 7;
    int ci = p & 127;
    wt[j] = dw[(co * 128 + ci) * 3 + k];
  }
}

// ---------------------------------------------------------------------------
// MFMA GEMM: C = A(MxK bf16) @ W(NxK bf16)^T. Block 256thr/4 waves, tile
// 64m x 64n, wave = 16 rows x 4 n-frags. mfma_f32_16x16x32_bf16 layouts:
//   A/B frag: row(lane&15), k = (lane>>4)*8 + j
//   C/D frag: col(lane&15), row = (lane>>4)*4 + reg
// MODE 0: fp32 store, ldc=N. MODE 1 (in_proj): col<256 -> bf16 xcpre,
// col>=256 -> bf16 silu -> zact.
// ---------------------------------------------------------------------------
template<int N, int K, int MODE>
__global__ __launch_bounds__(256) void mgemm(const short* __restrict__ A,
                                             const short* __restrict__ W,
                                             float* __restrict__ C,
                                             short* __restrict__ xcpre,
                                             short* __restrict__ zact) {
  const int m_base = blockIdx.x * 64;
  const int n_base = blockIdx.y * 64;
  const int wave = threadIdx.x >> 6;
  const int lane = threadIdx.x & 63;
  const int r16  = lane & 15;
  const int quad = lane >> 4;
  f32x4 acc[4] = {};
  const short* Ap = A + (size_t)(m_base + wave * 16 + r16) * K + quad * 8;
  const short* Wp = W + (size_t)(n_base + r16) * K + quad * 8;
#pragma unroll
  for (int k0 = 0; k0 < K; k0 += 32) {
    bf16x8 a = *(const bf16x8*)(Ap + k0);
#pragma unroll
    for (int j = 0; j < 4; ++j) {
      bf16x8 b = *(const bf16x8*)(Wp + (size_t)j * 16 * K + k0);
      acc[j] = __builtin_amdgcn_mfma_f32_16x16x32_bf16(a, b, acc[j], 0, 0, 0);
    }
  }
#pragma unroll
  for (int j = 0; j < 4; ++j) {
    const int col = n_base + j * 16 + r16;
#pragma unroll
    for (int r = 0; r < 4; ++r) {
      const int row = m_base + wave * 16 + quad * 4 + r;
      if (MODE == 0) {
        C[(size_t)row * N + col] = acc[j][r];
      } else {
        if (col < 256) {
          xcpre[(size_t)row * 256 + col] = f2s(acc[j][r]);
        } else {
          float v = acc[j][r];
          zact[(size_t)row * 256 + (col - 256)] = f2s(v / (1.f + __expf(-v)));
        }
      }
    }
  }
}

// ---------------------------------------------------------------------------
// VALU GEMM (x_dbl): C[row,gcol] = sum_k A[row,k]*W[gcol,k].
// ---------------------------------------------------------------------------
template<int NCOLS, int K, int NSTORE>
__global__ __launch_bounds__(256) void vgemm(const float* __restrict__ A,
                                             const float* __restrict__ W,
                                             float* __restrict__ C,
                                             int ldc) {
  constexpr int RPT = (32 * NCOLS) / 256;
  __shared__ float At[32][K];
  const int m0  = blockIdx.x * 32;
  const int tid = threadIdx.x;
  for (int idx = tid; idx < 32 * K; idx += 256) {
    int r = idx / K, k = idx % K;
    At[r][k] = A[(size_t)(m0 + r) * K + k];
  }
  __syncthreads();
  const int col  = tid % NCOLS;
  const int r0   = (tid / NCOLS) * RPT;
  const int gcol = blockIdx.y * NCOLS + col;
  if (col < NSTORE) {
    float acc[RPT];
#pragma unroll
    for (int r = 0; r < RPT; ++r) acc[r] = 0.f;
    const float* Wrow = W + (size_t)gcol * K;
    for (int k = 0; k < K; k += 4) {
      f32x4 w = *(const f32x4*)(Wrow + k);
#pragma unroll
      for (int r = 0; r < RPT; ++r) {
        const float* a = &At[r0 + r][k];
        acc[r] += a[0] * w[0] + a[1] * w[1] + a[2] * w[2] + a[3] * w[3];
      }
    }
#pragma unroll
    for (int r = 0; r < RPT; ++r)
      C[(size_t)(m0 + r0 + r) * ldc + gcol] = acc[r];
  }
}

// ---------------------------------------------------------------------------
// Depthwise causal conv (width 4) + bias + silu. xcpre bf16 -> xc fp32.
// ---------------------------------------------------------------------------
__global__ __launch_bounds__(256) void conv_silu(const short* __restrict__ xcpre,
                                                 const float* __restrict__ cw,
                                                 const float* __restrict__ cb,
                                                 float* __restrict__ xc) {
  int idx = blockIdx.x * 256 + threadIdx.x;   // (b,t,d), d fastest
  int d = idx & 255;
  int t = (idx >> 8) & 255;
  int b = idx >> 16;
  float acc = cb[d];
#pragma unroll
  for (int i = 0; i < 4; ++i) {
    int ts = t - 3 + i;
    if (ts >= 0)
      acc += s2f(xcpre[(size_t)(b * 256 + ts) * 256 + d]) * cw[d * 4 + i];
  }
  xc[idx] = acc / (1.f + __expf(-acc));
}

// ---------------------------------------------------------------------------
// scanA: local scan per (b, half, chunk of 32 t), h_in = 0. Emits per-state
// decay product P = prod(dA) and local end state E (bf16).
// Layout: P/E[chunk][(b*256+d)*16+n], chunk stride 524288 elems.
// ---------------------------------------------------------------------------
__global__ __launch_bounds__(128) void scanA(const float* __restrict__ xdbl,
                                             const float* __restrict__ xcu,
                                             const float* __restrict__ dtw,
                                             const float* __restrict__ dtb,
                                             const float* __restrict__ alog,
                                             short* __restrict__ Pb,
                                             short* __restrict__ Eb) {
  const int chunk = blockIdx.x & 7;
  const int half  = (blockIdx.x >> 3) & 1;
  const int b     = blockIdx.x >> 4;
  const int d  = half * 128 + threadIdx.x;
  const int t0 = chunk * 32;
  const size_t rb = (size_t)b * 256;
  __shared__ float S[32][24];                 // dt(8) | B(16)
  for (int i = threadIdx.x; i < 192; i += 128) {
    int row = i / 6, c4 = i - row * 6;
    f32x4 v = *(const f32x4*)(xdbl + (rb + t0 + row) * 64 + c4 * 4);
    *(f32x4*)(&S[row][c4 * 4]) = v;
  }
  float A[16];
#pragma unroll
  for (int n = 0; n < 16; ++n) A[n] = -__expf(alog[d * 16 + n]);
  float wdt[8];
#pragma unroll
  for (int j = 0; j < 8; ++j) wdt[j] = dtw[d * 8 + j];
  const float bdt = dtb[d];
  float P[16], h[16];
#pragma unroll
  for (int n = 0; n < 16; ++n) { P[n] = 1.f; h[n] = 0.f; }
  float uc[16], un[16];
  const size_t ubase = (rb + t0) * 256 + d;
#pragma unroll
  for (int i = 0; i < 16; ++i) un[i] = xcu[ubase + (size_t)i * 256];
  __syncthreads();
  for (int c = 0; c < 2; ++c) {
#pragma unroll
    for (int i = 0; i < 16; ++i) uc[i] = un[i];
    if (c == 0) {
#pragma unroll
      for (int i = 0; i < 16; ++i) un[i] = xcu[ubase + (size_t)(16 + i) * 256];
    }
#pragma unroll
    for (int tt = 0; tt < 16; ++tt) {
      const int t = c * 16 + tt;
      const f32x4* Sv = (const f32x4*)(&S[t][0]);
      f32x4 s0 = Sv[0], s1 = Sv[1];
      f32x4 b0 = Sv[2], b1 = Sv[3], b2 = Sv[4], b3 = Sv[5];
      float dacc = bdt
        + s0[0] * wdt[0] + s0[1] * wdt[1] + s0[2] * wdt[2] + s0[3] * wdt[3]
        + s1[0] * wdt[4] + s1[1] * wdt[5] + s1[2] * wdt[6] + s1[3] * wdt[7];
      const float delta = (dacc > 20.f) ? dacc : __logf(1.f + __expf(dacc));
      const float du = delta * uc[tt];
      float Bv[16] = { b0[0], b0[1], b0[2], b0[3], b1[0], b1[1], b1[2], b1[3],
                       b2[0], b2[1], b2[2], b2[3], b3[0], b3[1], b3[2], b3[3] };
#pragma unroll
      for (int n = 0; n < 16; ++n) {
        float dA = __expf(delta * A[n]);
        P[n] *= dA;
        h[n] = dA * h[n] + du * Bv[n];
      }
    }
  }
  const size_t o = (size_t)chunk * 524288 + ((size_t)(b * 256 + d)) * 16;
  bf16x8 p0, p1, e0, e1;
#pragma unroll
  for (int n = 0; n < 8; ++n) {
    p0[n] = f2s(P[n]);     p1[n] = f2s(P[8 + n]);
    e0[n] = f2s(h[n]);     e1[n] = f2s(h[8 + n]);
  }
  *(bf16x8*)(Pb + o)     = p0;  *(bf16x8*)(Pb + o + 8) = p1;
  *(bf16x8*)(Eb + o)     = e0;  *(bf16x8*)(Eb + o + 8) = e1;
}

// ---------------------------------------------------------------------------
// scanB: serial combine over 8 chunks per (b,d,n): hin(c)=P(c-1)hin(c-1)+E(c-1).
// Writes Hin over the P buffer (all P read into regs first).
// ---------------------------------------------------------------------------
__global__ __launch_bounds__(256) void scanB(short* __restrict__ Pb,
                                             const short* __restrict__ Eb) {
  const int i = blockIdx.x * 256 + threadIdx.x;   // 0 .. 524287
  float P[8], E[8];
#pragma unroll
  for (int c = 0; c < 8; ++c) {
    P[c] = s2f(Pb[(size_t)c * 524288 + i]);
    E[c] = s2f(Eb[(size_t)c * 524288 + i]);
  }
  float hin = 0.f;
  Pb[i] = 0;                                      // Hin[0] = 0
#pragma unroll
  for (int c = 1; c < 8; ++c) {
    hin = P[c - 1] * hin + E[c - 1];
    Pb[(size_t)c * 524288 + i] = f2s(hin);
  }
}

// ---------------------------------------------------------------------------
// scanC: exact re-scan of each chunk with h initialized to Hin; computes
// y = (C.h + u*D) * silu(z) -> yb (bf16).
// ---------------------------------------------------------------------------
__global__ __launch_bounds__(128) void scanC(const float* __restrict__ xdbl,
                                             const float* __restrict__ xcu,
                                             const short* __restrict__ Hin,
                                             const short* __restrict__ zact,
                                             const float* __restrict__ dtw,
                                             const float* __restrict__ dtb,
                                             const float* __restrict__ alog,
                                             const float* __restrict__ Dp,
                                             short* __restrict__ yb) {
  const int chunk = blockIdx.x & 7;
  const int half  = (blockIdx.x >> 3) & 1;
  const int b     = blockIdx.x >> 4;
  const int d  = half * 128 + threadIdx.x;
  const int t0 = chunk * 32;
  const size_t rb = (size_t)b * 256;
  __shared__ float S[32][40];                 // dt(8) | B(16) | C(16)
  for (int i = threadIdx.x; i < 320; i += 128) {
    int row = i / 10, c4 = i - row * 10;
    f32x4 v = *(const f32x4*)(xdbl + (rb + t0 + row) * 64 + c4 * 4);
    *(f32x4*)(&S[row][c4 * 4]) = v;
  }
  float A[16];
#pragma unroll
  for (int n = 0; n < 16; ++n) A[n] = -__expf(alog[d * 16 + n]);
  float wdt[8];
#pragma unroll
  for (int j = 0; j < 8; ++j) wdt[j] = dtw[d * 8 + j];
  const float bdt = dtb[d];
  const float Dv  = Dp[d];
  float h[16];
  {
    const size_t o = (size_t)chunk * 524288 + ((size_t)(b * 256 + d)) * 16;
#pragma unroll
    for (int n = 0; n < 16; ++n) h[n] = s2f(Hin[o + n]);
  }
  float uc[16], un[16], zc[16], zn[16];
  const size_t ubase = (rb + t0) * 256 + d;
#pragma unroll
  for (int i = 0; i < 16; ++i) {
    un[i] = xcu[ubase + (size_t)i * 256];
    zn[i] = s2f(zact[ubase + (size_t)i * 256]);
  }
  __syncthreads();
  for (int c = 0; c < 2; ++c) {
#pragma unroll
    for (int i = 0; i < 16; ++i) { uc[i] = un[i]; zc[i] = zn[i]; }
    if (c == 0) {
#pragma unroll
      for (int i = 0; i < 16; ++i) {
        un[i] = xcu[ubase + (size_t)(16 + i) * 256];
        zn[i] = s2f(zact[ubase + (size_t)(16 + i) * 256]);
      }
    }
#pragma unroll
    for (int tt = 0; tt < 16; ++tt) {
      const int t = c * 16 + tt;
      const f32x4* Sv = (const f32x4*)(&S[t][0]);
      f32x4 s0 = Sv[0], s1 = Sv[1];
      f32x4 b0 = Sv[2], b1 = Sv[3], b2 = Sv[4], b3 = Sv[5];
      f32x4 c0 = Sv[6], c1 = Sv[7], c2 = Sv[8], c3 = Sv[9];
      float dacc = bdt
        + s0[0] * wdt[0] + s0[1] * wdt[1] + s0[2] * wdt[2] + s0[3] * wdt[3]
        + s1[0] * wdt[4] + s1[1] * wdt[5] + s1[2] * wdt[6] + s1[3] * wdt[7];
      const float delta = (dacc > 20.f) ? dacc : __logf(1.f + __expf(dacc));
      const float u  = uc[tt];
      const float du = delta * u;
      float yt0 = 0.f, yt1 = 0.f, yt2 = 0.f, yt3 = 0.f;
      float Bv[16] = { b0[0], b0[1], b0[2], b0[3], b1[0], b1[1], b1[2], b1[3],
                       b2[0], b2[1], b2[2], b2[3], b3[0], b3[1], b3[2], b3[3] };
      float Cv[16] = { c0[0], c0[1], c0[2], c0[3], c1[0], c1[1], c1[2], c1[3],
                       c2[0], c2[1], c2[2], c2[3], c3[0], c3[1], c3[2], c3[3] };
#pragma unroll
      for (int n = 0; n < 16; ++n) {
        float dA = __expf(delta * A[n]);
        h[n] = dA * h[n] + du * Bv[n];
        float p = h[n] * Cv[n];
        if ((n & 3) == 0) yt0 += p;
        else if ((n & 3) == 1) yt1 += p;
        else if ((n & 3) == 2) yt2 += p;
        else yt3 += p;
      }
      const float yt = (yt0 + yt1) + (yt2 + yt3);
      yb[(rb + t0 + t) * 256 + d] = f2s((yt + u * Dv) * zc[tt]);
    }
  }
}

// ---------------------------------------------------------------------------
// Fused strided down-conv: hd[b,to,co] = sum_{k,ci} h1[b,2to+k-1,ci]*w[co,ci,k]
// + db[co]. Block = (b, 8 'to'), 128 threads; 17 h1 rows in LDS.
// ---------------------------------------------------------------------------
__global__ __launch_bounds__(128) void down_k(const float* __restrict__ h1,
                                              const float* __restrict__ wt,
                                              const float* __restrict__ db,
                                              float* __restrict__ hd) {
  const int b   = blockIdx.x >> 4;
  const int to0 = (blockIdx.x & 15) * 8;
  const int co  = threadIdx.x;
  __shared__ float hs[17][128];
  const int tbase = 2 * to0 - 1;
#pragma unroll
  for (int i = 0; i < 17; ++i) {
    int t = tbase + i;
    hs[i][co] = (t >= 0 && t < 256) ? h1[(size_t)(b * 256 + t) * 128 + co] : 0.f;
  }
  __syncthreads();
  float acc[8];
  const float bias = db[co];
#pragma unroll
  for (int r = 0; r < 8; ++r) acc[r] = bias;
  for (int j = 0; j < 384; ++j) {
    float w = wt[j * 128 + co];
    int k = j >> 7, ci = j & 127;
#pragma unroll
    for (int r = 0; r < 8; ++r) acc[r] += hs[2 * r + k][ci] * w;
  }
#pragma unroll
  for (int r = 0; r < 8; ++r)
    hd[(size_t)(b * 128 + to0 + r) * 128 + co] = acc[r];
}

// ---------------------------------------------------------------------------
// LayerNorm over last dim (128), eps 1e-5. One wave per row, 2 cols/thread.
// ---------------------------------------------------------------------------
__global__ __launch_bounds__(64) void ln_k(const float* __restrict__ hd,
                                           const float* __restrict__ g,
                                           const float* __restrict__ be,
                                           float* __restrict__ out) {
  int row = blockIdx.x;
  const float* r = hd + (size_t)row * 128;
  float v0 = r[threadIdx.x];
  float v1 = r[threadIdx.x + 64];
  float s = v0 + v1;
#pragma unroll
  for (int off = 32; off; off >>= 1) s += __shfl_xor(s, off);
  float mu = s * (1.0f / 128.0f);
  float d0 = v0 - mu, d1 = v1 - mu;
  float vs = d0 * d0 + d1 * d1;
#pragma unroll
  for (int off = 32; off; off >>= 1) vs += __shfl_xor(vs, off);
  float rstd = rsqrtf(vs * (1.0f / 128.0f) + 1e-5f);
  out[(size_t)row * 128 + threadIdx.x]      = d0 * rstd * g[threadIdx.x] + be[threadIdx.x];
  out[(size_t)row * 128 + threadIdx.x + 64] = d1 * rstd * g[threadIdx.x + 64] + be[threadIdx.x + 64];
}

// ---------------------------------------------------------------------------
// Workspace layout (bytes), peak 92,471,296 == proven-safe bound:
//   [0,16M)        xcpre bf16 (in_proj) -> reused as yb bf16 (scanC out)
//   [16M,32M)      zact bf16
//   [32M,64M)      xc fp32 (conv out; u) -> first 16MB reused as h1
//   [64M,72M)      xdbl fp32
//   [72M,80M)      xb bf16 (dead after in_proj) -> reused as P/Hin bf16
//   [80M,80.125M)  ipwb bf16 | opwb bf16
//   [80.19M,88.19M) E bf16
// wt (192KB fp32) staged in d_out spare quarter (overwritten by final copy).
// hd staged in d_out's x_skip half, consumed by LN before the x_skip copy.
// ---------------------------------------------------------------------------
static const size_t O_XCPRE = 0;            // also yb
static const size_t O_ZACT  = 16777216;
static const size_t O_XC    = 33554432;     // also h1 (first 16MB)
static const size_t O_XDBL  = 67108864;
static const size_t O_XB    = 75497472;     // also P / Hin (8,388,608 B)
static const size_t O_IPWB  = 83886080;     // 131,072 B
static const size_t O_OPWB  = 84017152;     //  65,536 B
static const size_t O_E     = 84082688;     // 8,388,608 B -> end 92,471,296

extern "C" void kernel_launch(void* const* d_in, const int* in_sizes, int n_in,
                              void* d_out, int out_size, void* d_ws, size_t ws_size,
                              hipStream_t stream) {
  const float* x    = (const float*)d_in[0];
  const float* ipw  = (const float*)d_in[1];
  const float* cw   = (const float*)d_in[2];
  const float* cb   = (const float*)d_in[3];
  const float* xpw  = (const float*)d_in[4];
  const float* dtw  = (const float*)d_in[5];
  const float* dtb  = (const float*)d_in[6];
  const float* alog = (const float*)d_in[7];
  const float* Dp   = (const float*)d_in[8];
  const float* opw  = (const float*)d_in[9];
  const float* dw   = (const float*)d_in[10];
  const float* db   = (const float*)d_in[11];
  const float* lng  = (const float*)d_in[12];
  const float* lnb  = (const float*)d_in[13];

  char*  ws    = (char*)d_ws;
  short* xcpre = (short*)(ws + O_XCPRE);
  short* yb    = (short*)(ws + O_XCPRE);  // alias (xcpre dead after conv)
  short* zact  = (short*)(ws + O_ZACT);
  float* xc    = (float*)(ws + O_XC);
  float* h1    = (float*)(ws + O_XC);     // alias (xc dead after scanC)
  float* xdbl  = (float*)(ws + O_XDBL);
  short* xb    = (short*)(ws + O_XB);
  short* Pb    = (short*)(ws + O_XB);     // alias (xb dead after in_proj)
  short* ipwb  = (short*)(ws + O_IPWB);
  short* opwb  = (short*)(ws + O_OPWB);
  short* Eb    = (short*)(ws + O_E);
  float* out   = (float*)d_out;
  float* hd    = out + 2097152;           // staged in x_skip half of d_out
  float* wt    = out + 4194304;           // spare quarter of x_skip half

  // 0. conversions / weight prep
  cvt_x<<<4096, 256, 0, stream>>>(x, xb);
  prep_w<<<576, 256, 0, stream>>>(ipw, opw, dw, ipwb, opwb, wt);
  // 1. in_proj MFMA (32768x512, K=128) -> bf16 xcpre + bf16 silu(z)
  mgemm<512, 128, 1><<<dim3(512, 8), 256, 0, stream>>>(
      xb, ipwb, nullptr, xcpre, zact);
  // 2. depthwise causal conv + silu -> xc (fp32)
  conv_silu<<<32768, 256, 0, stream>>>(xcpre, cw, cb, xc);
  // 3. x_dbl = xc @ x_proj_w^T (32768x40 in ldc=64)
  vgemm<64, 256, 40><<<dim3(1024, 1), 256, 0, stream>>>(xc, xpw, xdbl, 64);
  // 4. chunked parallel scan: A (local) -> B (combine) -> C (exact re-scan)
  scanA<<<2048, 128, 0, stream>>>(xdbl, xc, dtw, dtb, alog, Pb, Eb);
  scanB<<<2048, 256, 0, stream>>>(Pb, Eb);
  scanC<<<2048, 128, 0, stream>>>(xdbl, xc, Pb, zact, dtw, dtb, alog, Dp, yb);
  // 5. out_proj MFMA: h1 = y @ out_proj_w^T (32768x128, K=256), fp32 out
  mgemm<128, 256, 0><<<dim3(512, 2), 256, 0, stream>>>(
      yb, opwb, h1, nullptr, nullptr);
  // 6. fused strided down-conv -> hd (16384x128)
  down_k<<<2048, 128, 0, stream>>>(h1, wt, db, hd);
  // 7. LayerNorm -> output 0
  ln_k<<<16384, 64, 0, stream>>>(hd, lng, lnb, out);
  // 8. x_skip passthrough -> output 1 (overwrites hd/wt staging)
  hipMemcpyAsync(out + 2097152, x, (size_t)16777216, hipMemcpyDeviceToDevice, stream);
}

// Round 8
// 369.387 us; speedup vs baseline: 1.0595x; 1.0595x over previous
//
#include <hip/hip_runtime.h>
#include <hip/hip_bf16.h>

// Problem dims (fixed by reference)
//   B=128, T=256, D_MODEL=128, D_INNER=256, D_STATE=16, D_CONV=4, DT_RANK=8
// I/O dtype: float32. MFMA bf16 for in/out_proj. R8: scan rewritten as
// state-parallel single kernel (4 lanes per (b,d), 4 states/lane, quad
// shuffle-reduce) + delta precomputed by delta_k. No chunk duplication.
// Outputs: h (128,128,128) then x_skip (128,256,128), fp32, concatenated.

typedef __attribute__((ext_vector_type(8))) short bf16x8;
typedef __attribute__((ext_vector_type(4))) short bf16x4;
typedef __attribute__((ext_vector_type(4))) float f32x4;
using bf16 = __hip_bfloat16;

static __device__ __forceinline__ short f2s(float v) {
  union { bf16 b; short s; } u; u.b = (bf16)v; return u.s;
}
static __device__ __forceinline__ float s2f(short s) {
  union { short s; bf16 b; } u; u.s = s; return (float)u.b;
}

// ---------------------------------------------------------------------------
// fp32 -> bf16 convert for x (4,194,304 elems), 4/thread.
// ---------------------------------------------------------------------------
__global__ __launch_bounds__(256) void cvt_x(const float* __restrict__ x,
                                             short* __restrict__ xb) {
  int i = (blockIdx.x * 256 + threadIdx.x) * 4;
  f32x4 v = *(const f32x4*)(x + i);
  bf16x4 o;
  o[0] = f2s(v[0]); o[1] = f2s(v[1]); o[2] = f2s(v[2]); o[3] = f2s(v[3]);
  *(bf16x4*)(xb + i) = o;
}

// ---------------------------------------------------------------------------
// Weight prep: ipw(512x128)->bf16, opw(128x256)->bf16,
// down_w (co,ci,k) -> WT[(k*128+ci)*128+co] fp32 (staged in d_out spare).
// ---------------------------------------------------------------------------
__global__ __launch_bounds__(256) void prep_w(const float* __restrict__ ipw,
                                              const float* __restrict__ opw,
                                              const float* __restrict__ dw,
                                              short* __restrict__ ipwb,
                                              short* __restrict__ opwb,
                                              float* __restrict__ wt) {
  int idx = blockIdx.x * 256 + threadIdx.x;   // 0 .. 147455
  if (idx < 65536) {
    ipwb[idx] = f2s(ipw[idx]);
  } else if (idx < 98304) {
    int j = idx - 65536;
    opwb[j] = f2s(opw[j]);
  } else {
    int j = idx - 98304;          // (k*128+ci)*128 + co
    int co = j & 127;
    int p  = j >> 7;              // k*128+ci
    int k  = p >> 7;
    int ci = p & 127;
    wt[j] = dw[(co * 128 + ci) * 3 + k];
  }
}

// ---------------------------------------------------------------------------
// MFMA GEMM: C = A(MxK bf16) @ W(NxK bf16)^T. Block 256thr/4 waves, tile
// 64m x 64n, wave = 16 rows x 4 n-frags. mfma_f32_16x16x32_bf16 layouts:
//   A/B frag: row(lane&15), k = (lane>>4)*8 + j
//   C/D frag: col(lane&15), row = (lane>>4)*4 + reg
// MODE 0: fp32 store, ldc=N. MODE 1 (in_proj): col<256 -> bf16 xcpre,
// col>=256 -> bf16 silu -> zact.
// ---------------------------------------------------------------------------
template<int N, int K, int MODE>
__global__ __launch_bounds__(256) void mgemm(const short* __restrict__ A,
                                             const short* __restrict__ W,
                                             float* __restrict__ C,
                                             short* __restrict__ xcpre,
                                             short* __restrict__ zact) {
  const int m_base = blockIdx.x * 64;
  const int n_base = blockIdx.y * 64;
  const int wave = threadIdx.x >> 6;
  const int lane = threadIdx.x & 63;
  const int r16  = lane & 15;
  const int quad = lane >> 4;
  f32x4 acc[4] = {};
  const short* Ap = A + (size_t)(m_base + wave * 16 + r16) * K + quad * 8;
  const short* Wp = W + (size_t)(n_base + r16) * K + quad * 8;
#pragma unroll
  for (int k0 = 0; k0 < K; k0 += 32) {
    bf16x8 a = *(const bf16x8*)(Ap + k0);
#pragma unroll
    for (int j = 0; j < 4; ++j) {
      bf16x8 b = *(const bf16x8*)(Wp + (size_t)j * 16 * K + k0);
      acc[j] = __builtin_amdgcn_mfma_f32_16x16x32_bf16(a, b, acc[j], 0, 0, 0);
    }
  }
#pragma unroll
  for (int j = 0; j < 4; ++j) {
    const int col = n_base + j * 16 + r16;
#pragma unroll
    for (int r = 0; r < 4; ++r) {
      const int row = m_base + wave * 16 + quad * 4 + r;
      if (MODE == 0) {
        C[(size_t)row * N + col] = acc[j][r];
      } else {
        if (col < 256) {
          xcpre[(size_t)row * 256 + col] = f2s(acc[j][r]);
        } else {
          float v = acc[j][r];
          zact[(size_t)row * 256 + (col - 256)] = f2s(v / (1.f + __expf(-v)));
        }
      }
    }
  }
}

// ---------------------------------------------------------------------------
// VALU GEMM (x_dbl): C[row,gcol] = sum_k A[row,k]*W[gcol,k].
// ---------------------------------------------------------------------------
template<int NCOLS, int K, int NSTORE>
__global__ __launch_bounds__(256) void vgemm(const float* __restrict__ A,
                                             const float* __restrict__ W,
                                             float* __restrict__ C,
                                             int ldc) {
  constexpr int RPT = (32 * NCOLS) / 256;
  __shared__ float At[32][K];
  const int m0  = blockIdx.x * 32;
  const int tid = threadIdx.x;
  for (int idx = tid; idx < 32 * K; idx += 256) {
    int r = idx / K, k = idx % K;
    At[r][k] = A[(size_t)(m0 + r) * K + k];
  }
  __syncthreads();
  const int col  = tid % NCOLS;
  const int r0   = (tid / NCOLS) * RPT;
  const int gcol = blockIdx.y * NCOLS + col;
  if (col < NSTORE) {
    float acc[RPT];
#pragma unroll
    for (int r = 0; r < RPT; ++r) acc[r] = 0.f;
    const float* Wrow = W + (size_t)gcol * K;
    for (int k = 0; k < K; k += 4) {
      f32x4 w = *(const f32x4*)(Wrow + k);
#pragma unroll
      for (int r = 0; r < RPT; ++r) {
        const float* a = &At[r0 + r][k];
        acc[r] += a[0] * w[0] + a[1] * w[1] + a[2] * w[2] + a[3] * w[3];
      }
    }
#pragma unroll
    for (int r = 0; r < RPT; ++r)
      C[(size_t)(m0 + r0 + r) * ldc + gcol] = acc[r];
  }
}

// ---------------------------------------------------------------------------
// Depthwise causal conv (width 4) + bias + silu. xcpre bf16 -> xc fp32.
// ---------------------------------------------------------------------------
__global__ __launch_bounds__(256) void conv_silu(const short* __restrict__ xcpre,
                                                 const float* __restrict__ cw,
                                                 const float* __restrict__ cb,
                                                 float* __restrict__ xc) {
  int idx = blockIdx.x * 256 + threadIdx.x;   // (b,t,d), d fastest
  int d = idx & 255;
  int t = (idx >> 8) & 255;
  int b = idx >> 16;
  float acc = cb[d];
#pragma unroll
  for (int i = 0; i < 4; ++i) {
    int ts = t - 3 + i;
    if (ts >= 0)
      acc += s2f(xcpre[(size_t)(b * 256 + ts) * 256 + d]) * cw[d * 4 + i];
  }
  xc[idx] = acc / (1.f + __expf(-acc));
}

// ---------------------------------------------------------------------------
// delta_k: delta[b,t,d] = softplus(dt . dt_proj_w[d] + dt_proj_b[d]) -> bf16.
// One block per (b,t) row (256 threads = d); dt row (8 floats) is wave-
// broadcast from cache. ~3 us.
// ---------------------------------------------------------------------------
__global__ __launch_bounds__(256) void delta_k(const float* __restrict__ xdbl,
                                               const float* __restrict__ dtw,
                                               const float* __restrict__ dtb,
                                               short* __restrict__ deltab) {
  const int row = blockIdx.x;
  const int d   = threadIdx.x;
  const float* r = xdbl + (size_t)row * 64;
  float acc = dtb[d];
#pragma unroll
  for (int j = 0; j < 8; ++j) acc += r[j] * dtw[d * 8 + j];
  const float delta = (acc > 20.f) ? acc : __logf(1.f + __expf(acc));
  deltab[(size_t)row * 256 + d] = f2s(delta);
}

// ---------------------------------------------------------------------------
// scan4: state-parallel selective scan. Block = (b, group of 32 d), 128 thr
// = 32 d x 4 lanes; each lane owns 4 of the 16 states, serial over T=256.
// B/C staged in LDS (32 KB, broadcast b128 reads); u/delta/z in 8-step
// register prefetch chunks. yt reduced over the 4-lane quad via shfl_xor;
// lane q==0 writes y = (yt + u*D) * silu(z) -> yb bf16.
// ---------------------------------------------------------------------------
__global__ __launch_bounds__(128) void scan4(const float* __restrict__ xdbl,
                                             const float* __restrict__ xcu,
                                             const short* __restrict__ deltab,
                                             const short* __restrict__ zact,
                                             const float* __restrict__ alog,
                                             const float* __restrict__ Dp,
                                             short* __restrict__ yb) {
  const int g = blockIdx.x & 7;
  const int b = blockIdx.x >> 3;
  const int q = threadIdx.x & 3;
  const int d = g * 32 + (threadIdx.x >> 2);
  const size_t rb = (size_t)b * 256;
  __shared__ float S[256][32];                // B(16)|C(16) per t, 32 KB
  for (int i = threadIdx.x; i < 2048; i += 128) {
    int row = i >> 3, c4 = i & 7;
    f32x4 v = *(const f32x4*)(xdbl + (rb + row) * 64 + 8 + c4 * 4);
    *(f32x4*)(&S[row][c4 * 4]) = v;
  }
  float A[4];
#pragma unroll
  for (int n = 0; n < 4; ++n) A[n] = -__expf(alog[d * 16 + q * 4 + n]);
  const float Dv = Dp[d];
  float h[4] = {0.f, 0.f, 0.f, 0.f};
  const size_t base0 = rb * 256 + d;
  float uc[8], dc[8], zc[8], un[8], dn[8], zn[8];
#pragma unroll
  for (int i = 0; i < 8; ++i) {
    un[i] = xcu[base0 + (size_t)i * 256];
    dn[i] = s2f(deltab[base0 + (size_t)i * 256]);
    zn[i] = s2f(zact[base0 + (size_t)i * 256]);
  }
  __syncthreads();
  for (int c = 0; c < 32; ++c) {
#pragma unroll
    for (int i = 0; i < 8; ++i) { uc[i] = un[i]; dc[i] = dn[i]; zc[i] = zn[i]; }
    if (c + 1 < 32) {
      const size_t base = base0 + (size_t)(c + 1) * 8 * 256;
#pragma unroll
      for (int i = 0; i < 8; ++i) {
        un[i] = xcu[base + (size_t)i * 256];
        dn[i] = s2f(deltab[base + (size_t)i * 256]);
        zn[i] = s2f(zact[base + (size_t)i * 256]);
      }
    }
#pragma unroll
    for (int tt = 0; tt < 8; ++tt) {
      const int t = c * 8 + tt;
      const f32x4* Sv = (const f32x4*)(&S[t][0]);
      const f32x4 Bq = Sv[q];                 // B[q*4 .. q*4+3] (broadcast)
      const f32x4 Cq = Sv[4 + q];             // C[q*4 .. q*4+3]
      const float delta = dc[tt];
      const float u     = uc[tt];
      const float du    = delta * u;
      float yt = 0.f;
#pragma unroll
      for (int n = 0; n < 4; ++n) {
        const float dA = __expf(delta * A[n]);
        h[n] = dA * h[n] + du * Bq[n];
        yt += h[n] * Cq[n];
      }
      yt += __shfl_xor(yt, 1);
      yt += __shfl_xor(yt, 2);
      if (q == 0)
        yb[(rb + t) * 256 + d] = f2s((yt + u * Dv) * zc[tt]);
    }
  }
}

// ---------------------------------------------------------------------------
// Fused strided down-conv: hd[b,to,co] = sum_{k,ci} h1[b,2to+k-1,ci]*w[co,ci,k]
// + db[co]. Block = (b, 8 'to'), 128 threads; 17 h1 rows in LDS.
// ---------------------------------------------------------------------------
__global__ __launch_bounds__(128) void down_k(const float* __restrict__ h1,
                                              const float* __restrict__ wt,
                                              const float* __restrict__ db,
                                              float* __restrict__ hd) {
  const int b   = blockIdx.x >> 4;
  const int to0 = (blockIdx.x & 15) * 8;
  const int co  = threadIdx.x;
  __shared__ float hs[17][128];
  const int tbase = 2 * to0 - 1;
#pragma unroll
  for (int i = 0; i < 17; ++i) {
    int t = tbase + i;
    hs[i][co] = (t >= 0 && t < 256) ? h1[(size_t)(b * 256 + t) * 128 + co] : 0.f;
  }
  __syncthreads();
  float acc[8];
  const float bias = db[co];
#pragma unroll
  for (int r = 0; r < 8; ++r) acc[r] = bias;
  for (int j = 0; j < 384; ++j) {
    float w = wt[j * 128 + co];
    int k = j >> 7, ci = j & 127;
#pragma unroll
    for (int r = 0; r < 8; ++r) acc[r] += hs[2 * r + k][ci] * w;
  }
#pragma unroll
  for (int r = 0; r < 8; ++r)
    hd[(size_t)(b * 128 + to0 + r) * 128 + co] = acc[r];
}

// ---------------------------------------------------------------------------
// LayerNorm over last dim (128), eps 1e-5. One wave per row, 2 cols/thread.
// ---------------------------------------------------------------------------
__global__ __launch_bounds__(64) void ln_k(const float* __restrict__ hd,
                                           const float* __restrict__ g,
                                           const float* __restrict__ be,
                                           float* __restrict__ out) {
  int row = blockIdx.x;
  const float* r = hd + (size_t)row * 128;
  float v0 = r[threadIdx.x];
  float v1 = r[threadIdx.x + 64];
  float s = v0 + v1;
#pragma unroll
  for (int off = 32; off; off >>= 1) s += __shfl_xor(s, off);
  float mu = s * (1.0f / 128.0f);
  float d0 = v0 - mu, d1 = v1 - mu;
  float vs = d0 * d0 + d1 * d1;
#pragma unroll
  for (int off = 32; off; off >>= 1) vs += __shfl_xor(vs, off);
  float rstd = rsqrtf(vs * (1.0f / 128.0f) + 1e-5f);
  out[(size_t)row * 128 + threadIdx.x]      = d0 * rstd * g[threadIdx.x] + be[threadIdx.x];
  out[(size_t)row * 128 + threadIdx.x + 64] = d1 * rstd * g[threadIdx.x + 64] + be[threadIdx.x + 64];
}

// ---------------------------------------------------------------------------
// Workspace layout (bytes), peak 92,471,296 == proven-safe bound:
//   [0,16M)      xcpre bf16 (in_proj) -> reused as yb bf16 (scan out)
//   [16M,32M)    zact bf16
//   [32M,64M)    xc fp32 (conv out; u) -> first 16MB reused as h1
//   [64M,72M)    xdbl fp32
//   [72M,80M)    xb bf16 (dead after in_proj); [72M,88M) reused as delta bf16
//   [88M,88.2M)  ipwb bf16 | opwb bf16   (ends exactly at 92,471,296)
// wt (192KB fp32) staged in d_out spare quarter (overwritten by final copy).
// hd staged in d_out's x_skip half, consumed by LN before the x_skip copy.
// ---------------------------------------------------------------------------
static const size_t O_XCPRE = 0;            // also yb
static const size_t O_ZACT  = 16777216;
static const size_t O_XC    = 33554432;     // also h1 (first 16MB)
static const size_t O_XDBL  = 67108864;
static const size_t O_XB    = 75497472;     // also delta bf16 (16,777,216 B)
static const size_t O_IPWB  = 92274688;     // 131,072 B
static const size_t O_OPWB  = 92405760;     //  65,536 B -> end 92,471,296

extern "C" void kernel_launch(void* const* d_in, const int* in_sizes, int n_in,
                              void* d_out, int out_size, void* d_ws, size_t ws_size,
                              hipStream_t stream) {
  const float* x    = (const float*)d_in[0];
  const float* ipw  = (const float*)d_in[1];
  const float* cw   = (const float*)d_in[2];
  const float* cb   = (const float*)d_in[3];
  const float* xpw  = (const float*)d_in[4];
  const float* dtw  = (const float*)d_in[5];
  const float* dtb  = (const float*)d_in[6];
  const float* alog = (const float*)d_in[7];
  const float* Dp   = (const float*)d_in[8];
  const float* opw  = (const float*)d_in[9];
  const float* dw   = (const float*)d_in[10];
  const float* db   = (const float*)d_in[11];
  const float* lng  = (const float*)d_in[12];
  const float* lnb  = (const float*)d_in[13];

  char*  ws     = (char*)d_ws;
  short* xcpre  = (short*)(ws + O_XCPRE);
  short* yb     = (short*)(ws + O_XCPRE);  // alias (xcpre dead after conv)
  short* zact   = (short*)(ws + O_ZACT);
  float* xc     = (float*)(ws + O_XC);
  float* h1     = (float*)(ws + O_XC);     // alias (xc dead after scan4)
  float* xdbl   = (float*)(ws + O_XDBL);
  short* xb     = (short*)(ws + O_XB);
  short* deltab = (short*)(ws + O_XB);     // alias (xb dead after in_proj)
  short* ipwb   = (short*)(ws + O_IPWB);
  short* opwb   = (short*)(ws + O_OPWB);
  float* out    = (float*)d_out;
  float* hd     = out + 2097152;           // staged in x_skip half of d_out
  float* wt     = out + 4194304;           // spare quarter of x_skip half

  // 0. conversions / weight prep
  cvt_x<<<4096, 256, 0, stream>>>(x, xb);
  prep_w<<<576, 256, 0, stream>>>(ipw, opw, dw, ipwb, opwb, wt);
  // 1. in_proj MFMA (32768x512, K=128) -> bf16 xcpre + bf16 silu(z)
  mgemm<512, 128, 1><<<dim3(512, 8), 256, 0, stream>>>(
      xb, ipwb, nullptr, xcpre, zact);
  // 2. depthwise causal conv + silu -> xc (fp32)
  conv_silu<<<32768, 256, 0, stream>>>(xcpre, cw, cb, xc);
  // 3. x_dbl = xc @ x_proj_w^T (32768x40 in ldc=64)
  vgemm<64, 256, 40><<<dim3(1024, 1), 256, 0, stream>>>(xc, xpw, xdbl, 64);
  // 4. delta precompute, then state-parallel scan -> yb bf16
  delta_k<<<32768, 256, 0, stream>>>(xdbl, dtw, dtb, deltab);
  scan4<<<1024, 128, 0, stream>>>(xdbl, xc, deltab, zact, alog, Dp, yb);
  // 5. out_proj MFMA: h1 = y @ out_proj_w^T (32768x128, K=256), fp32 out
  mgemm<128, 256, 0><<<dim3(512, 2), 256, 0, stream>>>(
      yb, opwb, h1, nullptr, nullptr);
  // 6. fused strided down-conv -> hd (16384x128)
  down_k<<<2048, 128, 0, stream>>>(h1, wt, db, hd);
  // 7. LayerNorm -> output 0
  ln_k<<<16384, 64, 0, stream>>>(hd, lng, lnb, out);
  // 8. x_skip passthrough -> output 1 (overwrites hd/wt staging)
  hipMemcpyAsync(out + 2097152, x, (size_t)16777216, hipMemcpyDeviceToDevice, stream);
}

// Round 9
// 363.083 us; speedup vs baseline: 1.0779x; 1.0174x over previous
//
#include <hip/hip_runtime.h>
#include <hip/hip_bf16.h>

// Problem dims (fixed by reference)
//   B=128, T=256, D_MODEL=128, D_INNER=256, D_STATE=16, D_CONV=4, DT_RANK=8
// I/O dtype: float32. MFMA bf16 for in_proj/out_proj/x_proj. R9:
//  - scan4 LDS halved (B/C staged as bf16) -> 10 blocks/CU occupancy
//  - conv_silu emits bf16 xcb (halves conv->scan traffic)
//  - x_dbl GEMM on MFMA (zero-padded 64x256 bf16 x_proj_w in d_out spare)
// Outputs: h (128,128,128) then x_skip (128,256,128), fp32, concatenated.

typedef __attribute__((ext_vector_type(8))) short bf16x8;
typedef __attribute__((ext_vector_type(4))) short bf16x4;
typedef __attribute__((ext_vector_type(4))) float f32x4;
using bf16 = __hip_bfloat16;

static __device__ __forceinline__ short f2s(float v) {
  union { bf16 b; short s; } u; u.b = (bf16)v; return u.s;
}
static __device__ __forceinline__ float s2f(short s) {
  union { short s; bf16 b; } u; u.s = s; return (float)u.b;
}

// ---------------------------------------------------------------------------
// fp32 -> bf16 convert for x (4,194,304 elems), 4/thread.
// ---------------------------------------------------------------------------
__global__ __launch_bounds__(256) void cvt_x(const float* __restrict__ x,
                                             short* __restrict__ xb) {
  int i = (blockIdx.x * 256 + threadIdx.x) * 4;
  f32x4 v = *(const f32x4*)(x + i);
  bf16x4 o;
  o[0] = f2s(v[0]); o[1] = f2s(v[1]); o[2] = f2s(v[2]); o[3] = f2s(v[3]);
  *(bf16x4*)(xb + i) = o;
}

// ---------------------------------------------------------------------------
// Weight prep: ipw(512x128)->bf16, opw(128x256)->bf16,
// down_w (co,ci,k) -> WT[(k*128+ci)*128+co] fp32 (d_out spare),
// x_proj_w -> wxb (64x256 bf16, rows 40..63 zero; d_out spare).
// ---------------------------------------------------------------------------
__global__ __launch_bounds__(256) void prep_w(const float* __restrict__ ipw,
                                              const float* __restrict__ opw,
                                              const float* __restrict__ dw,
                                              const float* __restrict__ xpw,
                                              short* __restrict__ ipwb,
                                              short* __restrict__ opwb,
                                              float* __restrict__ wt,
                                              short* __restrict__ wxb) {
  int idx = blockIdx.x * 256 + threadIdx.x;   // 0 .. 163839
  if (idx < 65536) {
    ipwb[idx] = f2s(ipw[idx]);
  } else if (idx < 98304) {
    int j = idx - 65536;
    opwb[j] = f2s(opw[j]);
  } else if (idx < 147456) {
    int j = idx - 98304;          // (k*128+ci)*128 + co
    int co = j & 127;
    int p  = j >> 7;              // k*128+ci
    int k  = p >> 7;
    int ci = p & 127;
    wt[j] = dw[(co * 128 + ci) * 3 + k];
  } else {
    int j = idx - 147456;         // n*256 + k
    int n = j >> 8;
    wxb[j] = (n < 40) ? f2s(xpw[j]) : (short)0;
  }
}

// ---------------------------------------------------------------------------
// MFMA GEMM: C = A(MxK bf16) @ W(NxK bf16)^T. Block 256thr/4 waves, tile
// 64m x 64n, wave = 16 rows x 4 n-frags. mfma_f32_16x16x32_bf16 layouts:
//   A/B frag: row(lane&15), k = (lane>>4)*8 + j
//   C/D frag: col(lane&15), row = (lane>>4)*4 + reg
// MODE 0: fp32 store, ldc=N. MODE 1 (in_proj): col<256 -> bf16 xcpre,
// col>=256 -> bf16 silu -> zact.
// ---------------------------------------------------------------------------
template<int N, int K, int MODE>
__global__ __launch_bounds__(256) void mgemm(const short* __restrict__ A,
                                             const short* __restrict__ W,
                                             float* __restrict__ C,
                                             short* __restrict__ xcpre,
                                             short* __restrict__ zact) {
  const int m_base = blockIdx.x * 64;
  const int n_base = blockIdx.y * 64;
  const int wave = threadIdx.x >> 6;
  const int lane = threadIdx.x & 63;
  const int r16  = lane & 15;
  const int quad = lane >> 4;
  f32x4 acc[4] = {};
  const short* Ap = A + (size_t)(m_base + wave * 16 + r16) * K + quad * 8;
  const short* Wp = W + (size_t)(n_base + r16) * K + quad * 8;
#pragma unroll
  for (int k0 = 0; k0 < K; k0 += 32) {
    bf16x8 a = *(const bf16x8*)(Ap + k0);
#pragma unroll
    for (int j = 0; j < 4; ++j) {
      bf16x8 b = *(const bf16x8*)(Wp + (size_t)j * 16 * K + k0);
      acc[j] = __builtin_amdgcn_mfma_f32_16x16x32_bf16(a, b, acc[j], 0, 0, 0);
    }
  }
#pragma unroll
  for (int j = 0; j < 4; ++j) {
    const int col = n_base + j * 16 + r16;
#pragma unroll
    for (int r = 0; r < 4; ++r) {
      const int row = m_base + wave * 16 + quad * 4 + r;
      if (MODE == 0) {
        C[(size_t)row * N + col] = acc[j][r];
      } else {
        if (col < 256) {
          xcpre[(size_t)row * 256 + col] = f2s(acc[j][r]);
        } else {
          float v = acc[j][r];
          zact[(size_t)row * 256 + (col - 256)] = f2s(v / (1.f + __expf(-v)));
        }
      }
    }
  }
}

// ---------------------------------------------------------------------------
// Depthwise causal conv (width 4) + bias + silu. xcpre bf16 -> xcb bf16.
// ---------------------------------------------------------------------------
__global__ __launch_bounds__(256) void conv_silu(const short* __restrict__ xcpre,
                                                 const float* __restrict__ cw,
                                                 const float* __restrict__ cb,
                                                 short* __restrict__ xcb) {
  int idx = blockIdx.x * 256 + threadIdx.x;   // (b,t,d), d fastest
  int d = idx & 255;
  int t = (idx >> 8) & 255;
  int b = idx >> 16;
  float acc = cb[d];
#pragma unroll
  for (int i = 0; i < 4; ++i) {
    int ts = t - 3 + i;
    if (ts >= 0)
      acc += s2f(xcpre[(size_t)(b * 256 + ts) * 256 + d]) * cw[d * 4 + i];
  }
  xcb[idx] = f2s(acc / (1.f + __expf(-acc)));
}

// ---------------------------------------------------------------------------
// delta_k: delta[b,t,d] = softplus(dt . dt_proj_w[d] + dt_proj_b[d]) -> bf16.
// ---------------------------------------------------------------------------
__global__ __launch_bounds__(256) void delta_k(const float* __restrict__ xdbl,
                                               const float* __restrict__ dtw,
                                               const float* __restrict__ dtb,
                                               short* __restrict__ deltab) {
  const int row = blockIdx.x;
  const int d   = threadIdx.x;
  const float* r = xdbl + (size_t)row * 64;
  float acc = dtb[d];
#pragma unroll
  for (int j = 0; j < 8; ++j) acc += r[j] * dtw[d * 8 + j];
  const float delta = (acc > 20.f) ? acc : __logf(1.f + __expf(acc));
  deltab[(size_t)row * 256 + d] = f2s(delta);
}

// ---------------------------------------------------------------------------
// scan4: state-parallel selective scan. Block = (b, group of 32 d), 128 thr
// = 32 d x 4 lanes; each lane owns 4 of 16 states, serial over T=256.
// R9: B/C staged in LDS as bf16 (16 KB -> 10 blocks/CU); u from bf16 xcb.
// u/delta/z in 8-step register prefetch chunks; quad shfl_xor reduce.
// ---------------------------------------------------------------------------
__global__ __launch_bounds__(128) void scan4(const float* __restrict__ xdbl,
                                             const short* __restrict__ xcb,
                                             const short* __restrict__ deltab,
                                             const short* __restrict__ zact,
                                             const float* __restrict__ alog,
                                             const float* __restrict__ Dp,
                                             short* __restrict__ yb) {
  const int g = blockIdx.x & 7;
  const int b = blockIdx.x >> 3;
  const int q = threadIdx.x & 3;
  const int d = g * 32 + (threadIdx.x >> 2);
  const size_t rb = (size_t)b * 256;
  __shared__ short S[256][32];                // B(16)|C(16) bf16 per t, 16 KB
  for (int i = threadIdx.x; i < 2048; i += 128) {
    int row = i >> 3, c4 = i & 7;
    f32x4 v = *(const f32x4*)(xdbl + (rb + row) * 64 + 8 + c4 * 4);
    bf16x4 o;
    o[0] = f2s(v[0]); o[1] = f2s(v[1]); o[2] = f2s(v[2]); o[3] = f2s(v[3]);
    *(bf16x4*)(&S[row][c4 * 4]) = o;
  }
  float A[4];
#pragma unroll
  for (int n = 0; n < 4; ++n) A[n] = -__expf(alog[d * 16 + q * 4 + n]);
  const float Dv = Dp[d];
  float h[4] = {0.f, 0.f, 0.f, 0.f};
  const size_t base0 = rb * 256 + d;
  float uc[8], dc[8], zc[8], un[8], dn[8], zn[8];
#pragma unroll
  for (int i = 0; i < 8; ++i) {
    un[i] = s2f(xcb[base0 + (size_t)i * 256]);
    dn[i] = s2f(deltab[base0 + (size_t)i * 256]);
    zn[i] = s2f(zact[base0 + (size_t)i * 256]);
  }
  __syncthreads();
  for (int c = 0; c < 32; ++c) {
#pragma unroll
    for (int i = 0; i < 8; ++i) { uc[i] = un[i]; dc[i] = dn[i]; zc[i] = zn[i]; }
    if (c + 1 < 32) {
      const size_t base = base0 + (size_t)(c + 1) * 8 * 256;
#pragma unroll
      for (int i = 0; i < 8; ++i) {
        un[i] = s2f(xcb[base + (size_t)i * 256]);
        dn[i] = s2f(deltab[base + (size_t)i * 256]);
        zn[i] = s2f(zact[base + (size_t)i * 256]);
      }
    }
#pragma unroll
    for (int tt = 0; tt < 8; ++tt) {
      const int t = c * 8 + tt;
      const short* St = &S[t][0];
      bf16x4 Bq = *(const bf16x4*)(St + q * 4);        // broadcast ds_read
      bf16x4 Cq = *(const bf16x4*)(St + 16 + q * 4);
      const float delta = dc[tt];
      const float u     = uc[tt];
      const float du    = delta * u;
      float yt = 0.f;
#pragma unroll
      for (int n = 0; n < 4; ++n) {
        const float dA = __expf(delta * A[n]);
        h[n] = dA * h[n] + du * s2f(Bq[n]);
        yt += h[n] * s2f(Cq[n]);
      }
      yt += __shfl_xor(yt, 1);
      yt += __shfl_xor(yt, 2);
      if (q == 0)
        yb[(rb + t) * 256 + d] = f2s((yt + u * Dv) * zc[tt]);
    }
  }
}

// ---------------------------------------------------------------------------
// Fused strided down-conv: hd[b,to,co] = sum_{k,ci} h1[b,2to+k-1,ci]*w[co,ci,k]
// + db[co]. Block = (b, 8 'to'), 128 threads; 17 h1 rows in LDS.
// ---------------------------------------------------------------------------
__global__ __launch_bounds__(128) void down_k(const float* __restrict__ h1,
                                              const float* __restrict__ wt,
                                              const float* __restrict__ db,
                                              float* __restrict__ hd) {
  const int b   = blockIdx.x >> 4;
  const int to0 = (blockIdx.x & 15) * 8;
  const int co  = threadIdx.x;
  __shared__ float hs[17][128];
  const int tbase = 2 * to0 - 1;
#pragma unroll
  for (int i = 0; i < 17; ++i) {
    int t = tbase + i;
    hs[i][co] = (t >= 0 && t < 256) ? h1[(size_t)(b * 256 + t) * 128 + co] : 0.f;
  }
  __syncthreads();
  float acc[8];
  const float bias = db[co];
#pragma unroll
  for (int r = 0; r < 8; ++r) acc[r] = bias;
  for (int j = 0; j < 384; ++j) {
    float w = wt[j * 128 + co];
    int k = j >> 7, ci = j & 127;
#pragma unroll
    for (int r = 0; r < 8; ++r) acc[r] += hs[2 * r + k][ci] * w;
  }
#pragma unroll
  for (int r = 0; r < 8; ++r)
    hd[(size_t)(b * 128 + to0 + r) * 128 + co] = acc[r];
}

// ---------------------------------------------------------------------------
// LayerNorm over last dim (128), eps 1e-5. One wave per row, 2 cols/thread.
// ---------------------------------------------------------------------------
__global__ __launch_bounds__(64) void ln_k(const float* __restrict__ hd,
                                           const float* __restrict__ g,
                                           const float* __restrict__ be,
                                           float* __restrict__ out) {
  int row = blockIdx.x;
  const float* r = hd + (size_t)row * 128;
  float v0 = r[threadIdx.x];
  float v1 = r[threadIdx.x + 64];
  float s = v0 + v1;
#pragma unroll
  for (int off = 32; off; off >>= 1) s += __shfl_xor(s, off);
  float mu = s * (1.0f / 128.0f);
  float d0 = v0 - mu, d1 = v1 - mu;
  float vs = d0 * d0 + d1 * d1;
#pragma unroll
  for (int off = 32; off; off >>= 1) vs += __shfl_xor(vs, off);
  float rstd = rsqrtf(vs * (1.0f / 128.0f) + 1e-5f);
  out[(size_t)row * 128 + threadIdx.x]      = d0 * rstd * g[threadIdx.x] + be[threadIdx.x];
  out[(size_t)row * 128 + threadIdx.x + 64] = d1 * rstd * g[threadIdx.x + 64] + be[threadIdx.x + 64];
}

// ---------------------------------------------------------------------------
// Workspace layout (bytes), peak 92,471,296 == proven-safe bound:
//   [0,16M)      xcpre bf16 (in_proj) -> reused as yb bf16 (scan out)
//   [16M,32M)    zact bf16
//   [32M,48M)    xcb bf16 (conv out; u) -> reused as h1 fp32 after scan
//   [64M,72M)    xdbl fp32 (32768 x 64)
//   [72M,88M)    xb bf16 (dead after in_proj) -> reused as delta bf16
//   [88M,88.2M)  ipwb bf16 | opwb bf16   (ends exactly at 92,471,296)
// d_out spare stages: hd [2M,4M) fl; wt [4M,+49152) fl; wxb after wt (bf16).
// All d_out staging written every call, consumed before the x_skip copy.
// ---------------------------------------------------------------------------
static const size_t O_XCPRE = 0;            // also yb
static const size_t O_ZACT  = 16777216;
static const size_t O_XCB   = 33554432;     // also h1 fp32 (16MB)
static const size_t O_XDBL  = 67108864;
static const size_t O_XB    = 75497472;     // also delta bf16 (16,777,216 B)
static const size_t O_IPWB  = 92274688;     // 131,072 B
static const size_t O_OPWB  = 92405760;     //  65,536 B -> end 92,471,296

extern "C" void kernel_launch(void* const* d_in, const int* in_sizes, int n_in,
                              void* d_out, int out_size, void* d_ws, size_t ws_size,
                              hipStream_t stream) {
  const float* x    = (const float*)d_in[0];
  const float* ipw  = (const float*)d_in[1];
  const float* cw   = (const float*)d_in[2];
  const float* cb   = (const float*)d_in[3];
  const float* xpw  = (const float*)d_in[4];
  const float* dtw  = (const float*)d_in[5];
  const float* dtb  = (const float*)d_in[6];
  const float* alog = (const float*)d_in[7];
  const float* Dp   = (const float*)d_in[8];
  const float* opw  = (const float*)d_in[9];
  const float* dw   = (const float*)d_in[10];
  const float* db   = (const float*)d_in[11];
  const float* lng  = (const float*)d_in[12];
  const float* lnb  = (const float*)d_in[13];

  char*  ws     = (char*)d_ws;
  short* xcpre  = (short*)(ws + O_XCPRE);
  short* yb     = (short*)(ws + O_XCPRE);  // alias (xcpre dead after conv)
  short* zact   = (short*)(ws + O_ZACT);
  short* xcb    = (short*)(ws + O_XCB);
  float* h1     = (float*)(ws + O_XCB);    // alias (xcb dead after scan4)
  float* xdbl   = (float*)(ws + O_XDBL);
  short* xb     = (short*)(ws + O_XB);
  short* deltab = (short*)(ws + O_XB);     // alias (xb dead after in_proj)
  short* ipwb   = (short*)(ws + O_IPWB);
  short* opwb   = (short*)(ws + O_OPWB);
  float* out    = (float*)d_out;
  float* hd     = out + 2097152;           // staged in x_skip half of d_out
  float* wt     = out + 4194304;           // 49152 floats
  short* wxb    = (short*)(out + 4243456); // 16384 bf16 (8192 floats)

  // 0. conversions / weight prep
  cvt_x<<<4096, 256, 0, stream>>>(x, xb);
  prep_w<<<640, 256, 0, stream>>>(ipw, opw, dw, xpw, ipwb, opwb, wt, wxb);
  // 1. in_proj MFMA (32768x512, K=128) -> bf16 xcpre + bf16 silu(z)
  mgemm<512, 128, 1><<<dim3(512, 8), 256, 0, stream>>>(
      xb, ipwb, nullptr, xcpre, zact);
  // 2. depthwise causal conv + silu -> xcb (bf16)
  conv_silu<<<32768, 256, 0, stream>>>(xcpre, cw, cb, xcb);
  // 3. x_dbl MFMA: xcb @ wxb^T (32768x64, K=256) -> fp32 xdbl
  mgemm<64, 256, 0><<<dim3(512, 1), 256, 0, stream>>>(
      xcb, wxb, xdbl, nullptr, nullptr);
  // 4. delta precompute, then state-parallel scan -> yb bf16
  delta_k<<<32768, 256, 0, stream>>>(xdbl, dtw, dtb, deltab);
  scan4<<<1024, 128, 0, stream>>>(xdbl, xcb, deltab, zact, alog, Dp, yb);
  // 5. out_proj MFMA: h1 = y @ out_proj_w^T (32768x128, K=256), fp32 out
  mgemm<128, 256, 0><<<dim3(512, 2), 256, 0, stream>>>(
      yb, opwb, h1, nullptr, nullptr);
  // 6. fused strided down-conv -> hd (16384x128)
  down_k<<<2048, 128, 0, stream>>>(h1, wt, db, hd);
  // 7. LayerNorm -> output 0
  ln_k<<<16384, 64, 0, stream>>>(hd, lng, lnb, out);
  // 8. x_skip passthrough -> output 1 (overwrites hd/wt/wxb staging)
  hipMemcpyAsync(out + 2097152, x, (size_t)16777216, hipMemcpyDeviceToDevice, stream);
}

// Round 10
// 349.615 us; speedup vs baseline: 1.1194x; 1.0385x over previous
//
#include <hip/hip_runtime.h>
#include <hip/hip_bf16.h>

// Problem dims (fixed by reference)
//   B=128, T=256, D_MODEL=128, D_INNER=256, D_STATE=16, D_CONV=4, DT_RANK=8
// I/O dtype: float32. MFMA bf16 for in_proj/out_proj/x_proj. R10:
//  - scan4 __launch_bounds__(128,2): VGPR cap ~256 so the 48-reg u/delta/z
//    prefetch double-buffer stays in registers (R9's VGPR=44 broke it and
//    put HBM latency on the serial chain)
//  - scan4 S staging back to fp32 (no per-step bf16 converts; grid-bound
//    occupancy means 32KB LDS costs nothing)
// Outputs: h (128,128,128) then x_skip (128,256,128), fp32, concatenated.

typedef __attribute__((ext_vector_type(8))) short bf16x8;
typedef __attribute__((ext_vector_type(4))) short bf16x4;
typedef __attribute__((ext_vector_type(4))) float f32x4;
using bf16 = __hip_bfloat16;

static __device__ __forceinline__ short f2s(float v) {
  union { bf16 b; short s; } u; u.b = (bf16)v; return u.s;
}
static __device__ __forceinline__ float s2f(short s) {
  union { short s; bf16 b; } u; u.s = s; return (float)u.b;
}

// ---------------------------------------------------------------------------
// fp32 -> bf16 convert for x (4,194,304 elems), 4/thread.
// ---------------------------------------------------------------------------
__global__ __launch_bounds__(256) void cvt_x(const float* __restrict__ x,
                                             short* __restrict__ xb) {
  int i = (blockIdx.x * 256 + threadIdx.x) * 4;
  f32x4 v = *(const f32x4*)(x + i);
  bf16x4 o;
  o[0] = f2s(v[0]); o[1] = f2s(v[1]); o[2] = f2s(v[2]); o[3] = f2s(v[3]);
  *(bf16x4*)(xb + i) = o;
}

// ---------------------------------------------------------------------------
// Weight prep: ipw(512x128)->bf16, opw(128x256)->bf16,
// down_w (co,ci,k) -> WT[(k*128+ci)*128+co] fp32 (d_out spare),
// x_proj_w -> wxb (64x256 bf16, rows 40..63 zero; d_out spare).
// ---------------------------------------------------------------------------
__global__ __launch_bounds__(256) void prep_w(const float* __restrict__ ipw,
                                              const float* __restrict__ opw,
                                              const float* __restrict__ dw,
                                              const float* __restrict__ xpw,
                                              short* __restrict__ ipwb,
                                              short* __restrict__ opwb,
                                              float* __restrict__ wt,
                                              short* __restrict__ wxb) {
  int idx = blockIdx.x * 256 + threadIdx.x;   // 0 .. 163839
  if (idx < 65536) {
    ipwb[idx] = f2s(ipw[idx]);
  } else if (idx < 98304) {
    int j = idx - 65536;
    opwb[j] = f2s(opw[j]);
  } else if (idx < 147456) {
    int j = idx - 98304;          // (k*128+ci)*128 + co
    int co = j & 127;
    int p  = j >> 7;              // k*128+ci
    int k  = p >> 7;
    int ci = p & 127;
    wt[j] = dw[(co * 128 + ci) * 3 + k];
  } else {
    int j = idx - 147456;         // n*256 + k
    int n = j >> 8;
    wxb[j] = (n < 40) ? f2s(xpw[j]) : (short)0;
  }
}

// ---------------------------------------------------------------------------
// MFMA GEMM: C = A(MxK bf16) @ W(NxK bf16)^T. Block 256thr/4 waves, tile
// 64m x 64n, wave = 16 rows x 4 n-frags. mfma_f32_16x16x32_bf16 layouts:
//   A/B frag: row(lane&15), k = (lane>>4)*8 + j
//   C/D frag: col(lane&15), row = (lane>>4)*4 + reg
// MODE 0: fp32 store, ldc=N. MODE 1 (in_proj): col<256 -> bf16 xcpre,
// col>=256 -> bf16 silu -> zact.
// ---------------------------------------------------------------------------
template<int N, int K, int MODE>
__global__ __launch_bounds__(256) void mgemm(const short* __restrict__ A,
                                             const short* __restrict__ W,
                                             float* __restrict__ C,
                                             short* __restrict__ xcpre,
                                             short* __restrict__ zact) {
  const int m_base = blockIdx.x * 64;
  const int n_base = blockIdx.y * 64;
  const int wave = threadIdx.x >> 6;
  const int lane = threadIdx.x & 63;
  const int r16  = lane & 15;
  const int quad = lane >> 4;
  f32x4 acc[4] = {};
  const short* Ap = A + (size_t)(m_base + wave * 16 + r16) * K + quad * 8;
  const short* Wp = W + (size_t)(n_base + r16) * K + quad * 8;
#pragma unroll
  for (int k0 = 0; k0 < K; k0 += 32) {
    bf16x8 a = *(const bf16x8*)(Ap + k0);
#pragma unroll
    for (int j = 0; j < 4; ++j) {
      bf16x8 b = *(const bf16x8*)(Wp + (size_t)j * 16 * K + k0);
      acc[j] = __builtin_amdgcn_mfma_f32_16x16x32_bf16(a, b, acc[j], 0, 0, 0);
    }
  }
#pragma unroll
  for (int j = 0; j < 4; ++j) {
    const int col = n_base + j * 16 + r16;
#pragma unroll
    for (int r = 0; r < 4; ++r) {
      const int row = m_base + wave * 16 + quad * 4 + r;
      if (MODE == 0) {
        C[(size_t)row * N + col] = acc[j][r];
      } else {
        if (col < 256) {
          xcpre[(size_t)row * 256 + col] = f2s(acc[j][r]);
        } else {
          float v = acc[j][r];
          zact[(size_t)row * 256 + (col - 256)] = f2s(v / (1.f + __expf(-v)));
        }
      }
    }
  }
}

// ---------------------------------------------------------------------------
// Depthwise causal conv (width 4) + bias + silu. xcpre bf16 -> xcb bf16.
// ---------------------------------------------------------------------------
__global__ __launch_bounds__(256) void conv_silu(const short* __restrict__ xcpre,
                                                 const float* __restrict__ cw,
                                                 const float* __restrict__ cb,
                                                 short* __restrict__ xcb) {
  int idx = blockIdx.x * 256 + threadIdx.x;   // (b,t,d), d fastest
  int d = idx & 255;
  int t = (idx >> 8) & 255;
  int b = idx >> 16;
  float acc = cb[d];
#pragma unroll
  for (int i = 0; i < 4; ++i) {
    int ts = t - 3 + i;
    if (ts >= 0)
      acc += s2f(xcpre[(size_t)(b * 256 + ts) * 256 + d]) * cw[d * 4 + i];
  }
  xcb[idx] = f2s(acc / (1.f + __expf(-acc)));
}

// ---------------------------------------------------------------------------
// delta_k: delta[b,t,d] = softplus(dt . dt_proj_w[d] + dt_proj_b[d]) -> bf16.
// ---------------------------------------------------------------------------
__global__ __launch_bounds__(256) void delta_k(const float* __restrict__ xdbl,
                                               const float* __restrict__ dtw,
                                               const float* __restrict__ dtb,
                                               short* __restrict__ deltab) {
  const int row = blockIdx.x;
  const int d   = threadIdx.x;
  const float* r = xdbl + (size_t)row * 64;
  float acc = dtb[d];
#pragma unroll
  for (int j = 0; j < 8; ++j) acc += r[j] * dtw[d * 8 + j];
  const float delta = (acc > 20.f) ? acc : __logf(1.f + __expf(acc));
  deltab[(size_t)row * 256 + d] = f2s(delta);
}

// ---------------------------------------------------------------------------
// scan4: state-parallel selective scan. Block = (b, group of 32 d), 128 thr
// = 32 d x 4 lanes; each lane owns 4 of 16 states, serial over T=256.
// R10: __launch_bounds__(128,2) keeps the 48-reg u/delta/z prefetch
// double-buffer in registers (grid gives exactly 4 blocks/CU = 2 waves/EU);
// S staged fp32 (broadcast b128 reads, no per-step converts).
// ---------------------------------------------------------------------------
__global__ __launch_bounds__(128, 2) void scan4(const float* __restrict__ xdbl,
                                                const short* __restrict__ xcb,
                                                const short* __restrict__ deltab,
                                                const short* __restrict__ zact,
                                                const float* __restrict__ alog,
                                                const float* __restrict__ Dp,
                                                short* __restrict__ yb) {
  const int g = blockIdx.x & 7;
  const int b = blockIdx.x >> 3;
  const int q = threadIdx.x & 3;
  const int d = g * 32 + (threadIdx.x >> 2);
  const size_t rb = (size_t)b * 256;
  __shared__ float S[256][32];                // B(16)|C(16) fp32 per t, 32 KB
  for (int i = threadIdx.x; i < 2048; i += 128) {
    int row = i >> 3, c4 = i & 7;
    f32x4 v = *(const f32x4*)(xdbl + (rb + row) * 64 + 8 + c4 * 4);
    *(f32x4*)(&S[row][c4 * 4]) = v;
  }
  float A[4];
#pragma unroll
  for (int n = 0; n < 4; ++n) A[n] = -__expf(alog[d * 16 + q * 4 + n]);
  const float Dv = Dp[d];
  float h[4] = {0.f, 0.f, 0.f, 0.f};
  const size_t base0 = rb * 256 + d;
  float uc[8], dc[8], zc[8], un[8], dn[8], zn[8];
#pragma unroll
  for (int i = 0; i < 8; ++i) {
    un[i] = s2f(xcb[base0 + (size_t)i * 256]);
    dn[i] = s2f(deltab[base0 + (size_t)i * 256]);
    zn[i] = s2f(zact[base0 + (size_t)i * 256]);
  }
  __syncthreads();
  for (int c = 0; c < 32; ++c) {
#pragma unroll
    for (int i = 0; i < 8; ++i) { uc[i] = un[i]; dc[i] = dn[i]; zc[i] = zn[i]; }
    if (c + 1 < 32) {
      const size_t base = base0 + (size_t)(c + 1) * 8 * 256;
#pragma unroll
      for (int i = 0; i < 8; ++i) {
        un[i] = s2f(xcb[base + (size_t)i * 256]);
        dn[i] = s2f(deltab[base + (size_t)i * 256]);
        zn[i] = s2f(zact[base + (size_t)i * 256]);
      }
    }
#pragma unroll
    for (int tt = 0; tt < 8; ++tt) {
      const int t = c * 8 + tt;
      const f32x4* Sv = (const f32x4*)(&S[t][0]);
      const f32x4 Bq = Sv[q];                 // B[q*4 .. q*4+3] (broadcast)
      const f32x4 Cq = Sv[4 + q];             // C[q*4 .. q*4+3]
      const float delta = dc[tt];
      const float u     = uc[tt];
      const float du    = delta * u;
      float yt = 0.f;
#pragma unroll
      for (int n = 0; n < 4; ++n) {
        const float dA = __expf(delta * A[n]);
        h[n] = dA * h[n] + du * Bq[n];
        yt += h[n] * Cq[n];
      }
      yt += __shfl_xor(yt, 1);
      yt += __shfl_xor(yt, 2);
      if (q == 0)
        yb[(rb + t) * 256 + d] = f2s((yt + u * Dv) * zc[tt]);
    }
  }
}

// ---------------------------------------------------------------------------
// Fused strided down-conv: hd[b,to,co] = sum_{k,ci} h1[b,2to+k-1,ci]*w[co,ci,k]
// + db[co]. Block = (b, 8 'to'), 128 threads; 17 h1 rows in LDS.
// ---------------------------------------------------------------------------
__global__ __launch_bounds__(128) void down_k(const float* __restrict__ h1,
                                              const float* __restrict__ wt,
                                              const float* __restrict__ db,
                                              float* __restrict__ hd) {
  const int b   = blockIdx.x >> 4;
  const int to0 = (blockIdx.x & 15) * 8;
  const int co  = threadIdx.x;
  __shared__ float hs[17][128];
  const int tbase = 2 * to0 - 1;
#pragma unroll
  for (int i = 0; i < 17; ++i) {
    int t = tbase + i;
    hs[i][co] = (t >= 0 && t < 256) ? h1[(size_t)(b * 256 + t) * 128 + co] : 0.f;
  }
  __syncthreads();
  float acc[8];
  const float bias = db[co];
#pragma unroll
  for (int r = 0; r < 8; ++r) acc[r] = bias;
  for (int j = 0; j < 384; ++j) {
    float w = wt[j * 128 + co];
    int k = j >> 7, ci = j & 127;
#pragma unroll
    for (int r = 0; r < 8; ++r) acc[r] += hs[2 * r + k][ci] * w;
  }
#pragma unroll
  for (int r = 0; r < 8; ++r)
    hd[(size_t)(b * 128 + to0 + r) * 128 + co] = acc[r];
}

// ---------------------------------------------------------------------------
// LayerNorm over last dim (128), eps 1e-5. One wave per row, 2 cols/thread.
// ---------------------------------------------------------------------------
__global__ __launch_bounds__(64) void ln_k(const float* __restrict__ hd,
                                           const float* __restrict__ g,
                                           const float* __restrict__ be,
                                           float* __restrict__ out) {
  int row = blockIdx.x;
  const float* r = hd + (size_t)row * 128;
  float v0 = r[threadIdx.x];
  float v1 = r[threadIdx.x + 64];
  float s = v0 + v1;
#pragma unroll
  for (int off = 32; off; off >>= 1) s += __shfl_xor(s, off);
  float mu = s * (1.0f / 128.0f);
  float d0 = v0 - mu, d1 = v1 - mu;
  float vs = d0 * d0 + d1 * d1;
#pragma unroll
  for (int off = 32; off; off >>= 1) vs += __shfl_xor(vs, off);
  float rstd = rsqrtf(vs * (1.0f / 128.0f) + 1e-5f);
  out[(size_t)row * 128 + threadIdx.x]      = d0 * rstd * g[threadIdx.x] + be[threadIdx.x];
  out[(size_t)row * 128 + threadIdx.x + 64] = d1 * rstd * g[threadIdx.x + 64] + be[threadIdx.x + 64];
}

// ---------------------------------------------------------------------------
// Workspace layout (bytes), peak 92,471,296 == proven-safe bound:
//   [0,16M)      xcpre bf16 (in_proj) -> reused as yb bf16 (scan out)
//   [16M,32M)    zact bf16
//   [32M,48M)    xcb bf16 (conv out; u) -> reused as h1 fp32 after scan
//   [64M,72M)    xdbl fp32 (32768 x 64)
//   [72M,88M)    xb bf16 (dead after in_proj) -> reused as delta bf16
//   [88M,88.2M)  ipwb bf16 | opwb bf16   (ends exactly at 92,471,296)
// d_out spare stages: hd [2M,4M) fl; wt [4M,+49152) fl; wxb after wt (bf16).
// All d_out staging written every call, consumed before the x_skip copy.
// ---------------------------------------------------------------------------
static const size_t O_XCPRE = 0;            // also yb
static const size_t O_ZACT  = 16777216;
static const size_t O_XCB   = 33554432;     // also h1 fp32 (16MB)
static const size_t O_XDBL  = 67108864;
static const size_t O_XB    = 75497472;     // also delta bf16 (16,777,216 B)
static const size_t O_IPWB  = 92274688;     // 131,072 B
static const size_t O_OPWB  = 92405760;     //  65,536 B -> end 92,471,296

extern "C" void kernel_launch(void* const* d_in, const int* in_sizes, int n_in,
                              void* d_out, int out_size, void* d_ws, size_t ws_size,
                              hipStream_t stream) {
  const float* x    = (const float*)d_in[0];
  const float* ipw  = (const float*)d_in[1];
  const float* cw   = (const float*)d_in[2];
  const float* cb   = (const float*)d_in[3];
  const float* xpw  = (const float*)d_in[4];
  const float* dtw  = (const float*)d_in[5];
  const float* dtb  = (const float*)d_in[6];
  const float* alog = (const float*)d_in[7];
  const float* Dp   = (const float*)d_in[8];
  const float* opw  = (const float*)d_in[9];
  const float* dw   = (const float*)d_in[10];
  const float* db   = (const float*)d_in[11];
  const float* lng  = (const float*)d_in[12];
  const float* lnb  = (const float*)d_in[13];

  char*  ws     = (char*)d_ws;
  short* xcpre  = (short*)(ws + O_XCPRE);
  short* yb     = (short*)(ws + O_XCPRE);  // alias (xcpre dead after conv)
  short* zact   = (short*)(ws + O_ZACT);
  short* xcb    = (short*)(ws + O_XCB);
  float* h1     = (float*)(ws + O_XCB);    // alias (xcb dead after scan4)
  float* xdbl   = (float*)(ws + O_XDBL);
  short* xb     = (short*)(ws + O_XB);
  short* deltab = (short*)(ws + O_XB);     // alias (xb dead after in_proj)
  short* ipwb   = (short*)(ws + O_IPWB);
  short* opwb   = (short*)(ws + O_OPWB);
  float* out    = (float*)d_out;
  float* hd     = out + 2097152;           // staged in x_skip half of d_out
  float* wt     = out + 4194304;           // 49152 floats
  short* wxb    = (short*)(out + 4243456); // 16384 bf16 (8192 floats)

  // 0. conversions / weight prep
  cvt_x<<<4096, 256, 0, stream>>>(x, xb);
  prep_w<<<640, 256, 0, stream>>>(ipw, opw, dw, xpw, ipwb, opwb, wt, wxb);
  // 1. in_proj MFMA (32768x512, K=128) -> bf16 xcpre + bf16 silu(z)
  mgemm<512, 128, 1><<<dim3(512, 8), 256, 0, stream>>>(
      xb, ipwb, nullptr, xcpre, zact);
  // 2. depthwise causal conv + silu -> xcb (bf16)
  conv_silu<<<32768, 256, 0, stream>>>(xcpre, cw, cb, xcb);
  // 3. x_dbl MFMA: xcb @ wxb^T (32768x64, K=256) -> fp32 xdbl
  mgemm<64, 256, 0><<<dim3(512, 1), 256, 0, stream>>>(
      xcb, wxb, xdbl, nullptr, nullptr);
  // 4. delta precompute, then state-parallel scan -> yb bf16
  delta_k<<<32768, 256, 0, stream>>>(xdbl, dtw, dtb, deltab);
  scan4<<<1024, 128, 0, stream>>>(xdbl, xcb, deltab, zact, alog, Dp, yb);
  // 5. out_proj MFMA: h1 = y @ out_proj_w^T (32768x128, K=256), fp32 out
  mgemm<128, 256, 0><<<dim3(512, 2), 256, 0, stream>>>(
      yb, opwb, h1, nullptr, nullptr);
  // 6. fused strided down-conv -> hd (16384x128)
  down_k<<<2048, 128, 0, stream>>>(h1, wt, db, hd);
  // 7. LayerNorm -> output 0
  ln_k<<<16384, 64, 0, stream>>>(hd, lng, lnb, out);
  // 8. x_skip passthrough -> output 1 (overwrites hd/wt/wxb staging)
  hipMemcpyAsync(out + 2097152, x, (size_t)16777216, hipMemcpyDeviceToDevice, stream);
}

// Round 11
// 344.809 us; speedup vs baseline: 1.1350x; 1.0139x over previous
//
#include <hip/hip_runtime.h>
#include <hip/hip_bf16.h>

// Problem dims (fixed by reference)
//   B=128, T=256, D_MODEL=128, D_INNER=256, D_STATE=16, D_CONV=4, DT_RANK=8
// I/O dtype: float32. MFMA bf16 for in_proj/out_proj/x_proj. R11:
//  - u/delta/z transposed to (b,d,t) so scan5 loads ONE b128 per operand per
//    8 steps (R10's 24 stride-512B scalar loads/chunk defeated pipelining;
//    VGPR=68 proved the compiler sank them to point-of-use)
//  - conv_silu2/repack produce the transposed streams via LDS-transpose tiles
//  - cvt_x fused with x_skip copy (memcpy dispatch removed); wt/wxb staged in
//    out0 region (ln_k overwrites last); hd staged in ws
// Outputs: h (128,128,128) then x_skip (128,256,128), fp32, concatenated.

typedef __attribute__((ext_vector_type(8))) short bf16x8;
typedef __attribute__((ext_vector_type(4))) short bf16x4;
typedef __attribute__((ext_vector_type(4))) float f32x4;
using bf16 = __hip_bfloat16;

static __device__ __forceinline__ short f2s(float v) {
  union { bf16 b; short s; } u; u.b = (bf16)v; return u.s;
}
static __device__ __forceinline__ float s2f(short s) {
  union { short s; bf16 b; } u; u.s = s; return (float)u.b;
}

// ---------------------------------------------------------------------------
// cvt_x: x fp32 -> bf16 xb AND x_skip passthrough (out1), 4 elems/thread.
// ---------------------------------------------------------------------------
__global__ __launch_bounds__(256) void cvt_x(const float* __restrict__ x,
                                             short* __restrict__ xb,
                                             float* __restrict__ out1) {
  int i = (blockIdx.x * 256 + threadIdx.x) * 4;
  f32x4 v = *(const f32x4*)(x + i);
  bf16x4 o;
  o[0] = f2s(v[0]); o[1] = f2s(v[1]); o[2] = f2s(v[2]); o[3] = f2s(v[3]);
  *(bf16x4*)(xb + i) = o;
  *(f32x4*)(out1 + i) = v;
}

// ---------------------------------------------------------------------------
// Weight prep: ipw(512x128)->bf16 (ws), opw(128x256)->bf16 (ws),
// down_w (co,ci,k) -> WT[(k*128+ci)*128+co] fp32 (out0 region),
// x_proj_w -> wxb (64x256 bf16, rows 40..63 zero; out0 region).
// out0 staging is safe: ln_k writes out0 LAST, after all consumers.
// ---------------------------------------------------------------------------
__global__ __launch_bounds__(256) void prep_w(const float* __restrict__ ipw,
                                              const float* __restrict__ opw,
                                              const float* __restrict__ dw,
                                              const float* __restrict__ xpw,
                                              short* __restrict__ ipwb,
                                              short* __restrict__ opwb,
                                              float* __restrict__ wt,
                                              short* __restrict__ wxb) {
  int idx = blockIdx.x * 256 + threadIdx.x;   // 0 .. 163839
  if (idx < 65536) {
    ipwb[idx] = f2s(ipw[idx]);
  } else if (idx < 98304) {
    int j = idx - 65536;
    opwb[j] = f2s(opw[j]);
  } else if (idx < 147456) {
    int j = idx - 98304;          // (k*128+ci)*128 + co
    int co = j & 127;
    int p  = j >> 7;              // k*128+ci
    int k  = p >> 7;
    int ci = p & 127;
    wt[j] = dw[(co * 128 + ci) * 3 + k];
  } else {
    int j = idx - 147456;         // n*256 + k
    int n = j >> 8;
    wxb[j] = (n < 40) ? f2s(xpw[j]) : (short)0;
  }
}

// ---------------------------------------------------------------------------
// MFMA GEMM: C = A(MxK bf16) @ W(NxK bf16)^T. Block 256thr/4 waves, tile
// 64m x 64n, wave = 16 rows x 4 n-frags. mfma_f32_16x16x32_bf16 layouts:
//   A/B frag: row(lane&15), k = (lane>>4)*8 + j
//   C/D frag: col(lane&15), row = (lane>>4)*4 + reg
// MODE 0: fp32 store, ldc=N. MODE 1 (in_proj): col<256 -> bf16 xcpre,
// col>=256 -> bf16 silu -> zact.
// ---------------------------------------------------------------------------
template<int N, int K, int MODE>
__global__ __launch_bounds__(256) void mgemm(const short* __restrict__ A,
                                             const short* __restrict__ W,
                                             float* __restrict__ C,
                                             short* __restrict__ xcpre,
                                             short* __restrict__ zact) {
  const int m_base = blockIdx.x * 64;
  const int n_base = blockIdx.y * 64;
  const int wave = threadIdx.x >> 6;
  const int lane = threadIdx.x & 63;
  const int r16  = lane & 15;
  const int quad = lane >> 4;
  f32x4 acc[4] = {};
  const short* Ap = A + (size_t)(m_base + wave * 16 + r16) * K + quad * 8;
  const short* Wp = W + (size_t)(n_base + r16) * K + quad * 8;
#pragma unroll
  for (int k0 = 0; k0 < K; k0 += 32) {
    bf16x8 a = *(const bf16x8*)(Ap + k0);
#pragma unroll
    for (int j = 0; j < 4; ++j) {
      bf16x8 b = *(const bf16x8*)(Wp + (size_t)j * 16 * K + k0);
      acc[j] = __builtin_amdgcn_mfma_f32_16x16x32_bf16(a, b, acc[j], 0, 0, 0);
    }
  }
#pragma unroll
  for (int j = 0; j < 4; ++j) {
    const int col = n_base + j * 16 + r16;
#pragma unroll
    for (int r = 0; r < 4; ++r) {
      const int row = m_base + wave * 16 + quad * 4 + r;
      if (MODE == 0) {
        C[(size_t)row * N + col] = acc[j][r];
      } else {
        if (col < 256) {
          xcpre[(size_t)row * 256 + col] = f2s(acc[j][r]);
        } else {
          float v = acc[j][r];
          zact[(size_t)row * 256 + (col - 256)] = f2s(v / (1.f + __expf(-v)));
        }
      }
    }
  }
}

// ---------------------------------------------------------------------------
// conv_silu2: depthwise causal conv (width 4) + bias + silu. Block = (b,
// 64-d tile), 256 thr = 64 d-lanes x 4 t-groups of 64. Each thread runs its
// t-range serially (coalesced 128B/wave input reads, 3-tap history in regs).
// Emits xcb (b,t,d) for the x_proj GEMM and, via LDS transpose, xcT (b,d,t)
// with 1KB-coalesced b128 stores.
// ---------------------------------------------------------------------------
__global__ __launch_bounds__(256) void conv_silu2(const short* __restrict__ xcpre,
                                                  const float* __restrict__ cw,
                                                  const float* __restrict__ cb,
                                                  short* __restrict__ xcb,
                                                  short* __restrict__ xcT) {
  const int b  = blockIdx.x >> 2;
  const int dt = (blockIdx.x & 3) * 64;
  const int tg = threadIdx.x >> 6;
  const int dl = threadIdx.x & 63;
  const int d  = dt + dl;
  const int t0 = tg * 64;
  __shared__ short L[64][264];                 // [d][t] bf16, stride 264 (16B-aligned)
  const float w0 = cw[d * 4], w1 = cw[d * 4 + 1], w2 = cw[d * 4 + 2], w3 = cw[d * 4 + 3];
  const float bias = cb[d];
  const size_t base = (size_t)b * 65536 + d;   // xcpre[(b,t,d)] = base + t*256
  float p0 = (t0 >= 3) ? s2f(xcpre[base + (size_t)(t0 - 3) * 256]) : 0.f;
  float p1 = (t0 >= 2) ? s2f(xcpre[base + (size_t)(t0 - 2) * 256]) : 0.f;
  float p2 = (t0 >= 1) ? s2f(xcpre[base + (size_t)(t0 - 1) * 256]) : 0.f;
  for (int t = t0; t < t0 + 64; ++t) {
    float cur = s2f(xcpre[base + (size_t)t * 256]);
    float acc = bias + p0 * w0 + p1 * w1 + p2 * w2 + cur * w3;
    short s = f2s(acc / (1.f + __expf(-acc)));
    xcb[base + (size_t)t * 256] = s;           // coalesced per t
    L[dl][t] = s;
    p0 = p1; p1 = p2; p2 = cur;
  }
  __syncthreads();
  // transpose write-out: per round, wave covers 2 full d-rows -> 1KB contig
#pragma unroll
  for (int r8 = 0; r8 < 8; ++r8) {
    const int dw = r8 * 8 + (threadIdx.x >> 5);
    const int tc = threadIdx.x & 31;
    bf16x8 v = *(const bf16x8*)(&L[dw][tc * 8]);
    *(bf16x8*)(xcT + ((size_t)b * 256 + dt + dw) * 256 + tc * 8) = v;
  }
}

// ---------------------------------------------------------------------------
// repack: delta = softplus(dt . dt_proj_w[d] + b[d]) and z-transpose.
// Same block/tile structure as conv_silu2; emits dT,zT in (b,d,t) bf16.
// ---------------------------------------------------------------------------
__global__ __launch_bounds__(256) void repack(const float* __restrict__ xdbl,
                                              const short* __restrict__ zact,
                                              const float* __restrict__ dtw,
                                              const float* __restrict__ dtb,
                                              short* __restrict__ dT,
                                              short* __restrict__ zT) {
  const int b  = blockIdx.x >> 2;
  const int dt = (blockIdx.x & 3) * 64;
  const int tg = threadIdx.x >> 6;
  const int dl = threadIdx.x & 63;
  const int d  = dt + dl;
  const int t0 = tg * 64;
  __shared__ short Ld[64][264], Lz[64][264];   // 2 x 33,792 B
  float wd[8];
#pragma unroll
  for (int j = 0; j < 8; ++j) wd[j] = dtw[d * 8 + j];
  const float bd = dtb[d];
  for (int t = t0; t < t0 + 64; ++t) {
    const float* r = xdbl + (size_t)(b * 256 + t) * 64;
    float acc = bd;
#pragma unroll
    for (int j = 0; j < 8; ++j) acc += r[j] * wd[j];
    const float delta = (acc > 20.f) ? acc : __logf(1.f + __expf(acc));
    Ld[dl][t] = f2s(delta);
    Lz[dl][t] = zact[(size_t)b * 65536 + (size_t)t * 256 + d];
  }
  __syncthreads();
#pragma unroll
  for (int r8 = 0; r8 < 8; ++r8) {
    const int dw = r8 * 8 + (threadIdx.x >> 5);
    const int tc = threadIdx.x & 31;
    const size_t o = ((size_t)b * 256 + dt + dw) * 256 + tc * 8;
    *(bf16x8*)(dT + o) = *(const bf16x8*)(&Ld[dw][tc * 8]);
    *(bf16x8*)(zT + o) = *(const bf16x8*)(&Lz[dw][tc * 8]);
  }
}

// ---------------------------------------------------------------------------
// scan5: state-parallel selective scan. Block = (b, group of 32 d), 128 thr
// = 32 d x 4 lanes; lane owns 4 of 16 states, serial T=256. u/delta/z now
// t-contiguous (b,d,t): ONE b128 load each per 8-step chunk, register
// double-buffered. S (B/C fp32) in LDS from xdbl. Quad shfl_xor reduce.
// ---------------------------------------------------------------------------
__global__ __launch_bounds__(128, 2) void scan5(const float* __restrict__ xdbl,
                                                const short* __restrict__ xcT,
                                                const short* __restrict__ dT,
                                                const short* __restrict__ zT,
                                                const float* __restrict__ alog,
                                                const float* __restrict__ Dp,
                                                short* __restrict__ yb) {
  const int g = blockIdx.x & 7;
  const int b = blockIdx.x >> 3;
  const int q = threadIdx.x & 3;
  const int d = g * 32 + (threadIdx.x >> 2);
  const size_t rb = (size_t)b * 256;
  __shared__ float S[256][32];                // B(16)|C(16) fp32 per t, 32 KB
  for (int i = threadIdx.x; i < 2048; i += 128) {
    int row = i >> 3, c4 = i & 7;
    f32x4 v = *(const f32x4*)(xdbl + (rb + row) * 64 + 8 + c4 * 4);
    *(f32x4*)(&S[row][c4 * 4]) = v;
  }
  float A[4];
#pragma unroll
  for (int n = 0; n < 4; ++n) A[n] = -__expf(alog[d * 16 + q * 4 + n]);
  const float Dv = Dp[d];
  float h[4] = {0.f, 0.f, 0.f, 0.f};
  const size_t tb = ((size_t)b * 256 + d) * 256;   // t-row base (b,d,t)
  bf16x8 ucur = *(const bf16x8*)(xcT + tb);
  bf16x8 dcur = *(const bf16x8*)(dT + tb);
  bf16x8 zcur = *(const bf16x8*)(zT + tb);
  __syncthreads();
  for (int c = 0; c < 32; ++c) {
    bf16x8 unx = ucur, dnx = dcur, znx = zcur;
    if (c + 1 < 32) {
      unx = *(const bf16x8*)(xcT + tb + (c + 1) * 8);
      dnx = *(const bf16x8*)(dT + tb + (c + 1) * 8);
      znx = *(const bf16x8*)(zT + tb + (c + 1) * 8);
    }
#pragma unroll
    for (int tt = 0; tt < 8; ++tt) {
      const int t = c * 8 + tt;
      const f32x4* Sv = (const f32x4*)(&S[t][0]);
      const f32x4 Bq = Sv[q];
      const f32x4 Cq = Sv[4 + q];
      const float delta = s2f(dcur[tt]);
      const float u     = s2f(ucur[tt]);
      const float du    = delta * u;
      float yt = 0.f;
#pragma unroll
      for (int n = 0; n < 4; ++n) {
        const float dA = __expf(delta * A[n]);
        h[n] = dA * h[n] + du * Bq[n];
        yt += h[n] * Cq[n];
      }
      yt += __shfl_xor(yt, 1);
      yt += __shfl_xor(yt, 2);
      if (q == 0)
        yb[(rb + t) * 256 + d] = f2s((yt + u * Dv) * s2f(zcur[tt]));
    }
    ucur = unx; dcur = dnx; zcur = znx;
  }
}

// ---------------------------------------------------------------------------
// Fused strided down-conv: hd[b,to,co] = sum_{k,ci} h1[b,2to+k-1,ci]*w[co,ci,k]
// + db[co]. Block = (b, 8 'to'), 128 threads; 17 h1 rows in LDS.
// ---------------------------------------------------------------------------
__global__ __launch_bounds__(128) void down_k(const float* __restrict__ h1,
                                              const float* __restrict__ wt,
                                              const float* __restrict__ db,
                                              float* __restrict__ hd) {
  const int b   = blockIdx.x >> 4;
  const int to0 = (blockIdx.x & 15) * 8;
  const int co  = threadIdx.x;
  __shared__ float hs[17][128];
  const int tbase = 2 * to0 - 1;
#pragma unroll
  for (int i = 0; i < 17; ++i) {
    int t = tbase + i;
    hs[i][co] = (t >= 0 && t < 256) ? h1[(size_t)(b * 256 + t) * 128 + co] : 0.f;
  }
  __syncthreads();
  float acc[8];
  const float bias = db[co];
#pragma unroll
  for (int r = 0; r < 8; ++r) acc[r] = bias;
  for (int j = 0; j < 384; ++j) {
    float w = wt[j * 128 + co];
    int k = j >> 7, ci = j & 127;
#pragma unroll
    for (int r = 0; r < 8; ++r) acc[r] += hs[2 * r + k][ci] * w;
  }
#pragma unroll
  for (int r = 0; r < 8; ++r)
    hd[(size_t)(b * 128 + to0 + r) * 128 + co] = acc[r];
}

// ---------------------------------------------------------------------------
// LayerNorm over last dim (128), eps 1e-5. One wave per row, 2 cols/thread.
// ---------------------------------------------------------------------------
__global__ __launch_bounds__(64) void ln_k(const float* __restrict__ hd,
                                           const float* __restrict__ g,
                                           const float* __restrict__ be,
                                           float* __restrict__ out) {
  int row = blockIdx.x;
  const float* r = hd + (size_t)row * 128;
  float v0 = r[threadIdx.x];
  float v1 = r[threadIdx.x + 64];
  float s = v0 + v1;
#pragma unroll
  for (int off = 32; off; off >>= 1) s += __shfl_xor(s, off);
  float mu = s * (1.0f / 128.0f);
  float d0 = v0 - mu, d1 = v1 - mu;
  float vs = d0 * d0 + d1 * d1;
#pragma unroll
  for (int off = 32; off; off >>= 1) vs += __shfl_xor(vs, off);
  float rstd = rsqrtf(vs * (1.0f / 128.0f) + 1e-5f);
  out[(size_t)row * 128 + threadIdx.x]      = d0 * rstd * g[threadIdx.x] + be[threadIdx.x];
  out[(size_t)row * 128 + threadIdx.x + 64] = d1 * rstd * g[threadIdx.x + 64] + be[threadIdx.x + 64];
}

// ---------------------------------------------------------------------------
// Workspace layout (bytes), peak 92,471,296 == proven-safe bound:
//   [0,16M)      xcpre bf16 (in_proj->conv) -> yb bf16 (scan->out_proj)
//                -> hd fp32 8.4MB (down_k->ln)
//   [16M,32M)    xcT bf16 (conv->scan)
//   [32M,48M)    zact bf16 (in_proj->repack)
//   [48M,64M)    xcb bf16 (conv->xproj) -> dT bf16 (repack->scan)
//                -> h1 fp32 (out_proj->down_k)
//   [64M,72M)    xdbl fp32 (xproj->scan)
//   [72M,88M)    xb bf16 8.4MB (cvt->in_proj) -> zT bf16 (repack->scan)
//   [88M,88.2M)  ipwb | opwb bf16  (ends exactly at 92,471,296)
// d_out staging: wt (192KB fp32) + wxb (32KB bf16) in OUT0 region
// (ln_k writes out0 LAST); out1 written once by cvt_x.
// ---------------------------------------------------------------------------
static const size_t O_XCPRE = 0;            // also yb, then hd
static const size_t O_XCT   = 16777216;
static const size_t O_ZACT  = 33554432;
static const size_t O_XCB   = 50331648;     // also dT, then h1
static const size_t O_XDBL  = 67108864;
static const size_t O_XB    = 75497472;     // also zT (16,777,216 B)
static const size_t O_IPWB  = 92274688;     // 131,072 B
static const size_t O_OPWB  = 92405760;     //  65,536 B -> end 92,471,296

extern "C" void kernel_launch(void* const* d_in, const int* in_sizes, int n_in,
                              void* d_out, int out_size, void* d_ws, size_t ws_size,
                              hipStream_t stream) {
  const float* x    = (const float*)d_in[0];
  const float* ipw  = (const float*)d_in[1];
  const float* cw   = (const float*)d_in[2];
  const float* cb   = (const float*)d_in[3];
  const float* xpw  = (const float*)d_in[4];
  const float* dtw  = (const float*)d_in[5];
  const float* dtb  = (const float*)d_in[6];
  const float* alog = (const float*)d_in[7];
  const float* Dp   = (const float*)d_in[8];
  const float* opw  = (const float*)d_in[9];
  const float* dw   = (const float*)d_in[10];
  const float* db   = (const float*)d_in[11];
  const float* lng  = (const float*)d_in[12];
  const float* lnb  = (const float*)d_in[13];

  char*  ws     = (char*)d_ws;
  short* xcpre  = (short*)(ws + O_XCPRE);
  short* yb     = (short*)(ws + O_XCPRE);  // alias (xcpre dead after conv)
  float* hd     = (float*)(ws + O_XCPRE);  // alias (yb dead after out_proj)
  short* xcT    = (short*)(ws + O_XCT);
  short* zact   = (short*)(ws + O_ZACT);
  short* xcb    = (short*)(ws + O_XCB);
  short* dT     = (short*)(ws + O_XCB);    // alias (xcb dead after xproj)
  float* h1     = (float*)(ws + O_XCB);    // alias (dT dead after scan)
  float* xdbl   = (float*)(ws + O_XDBL);
  short* xb     = (short*)(ws + O_XB);
  short* zT     = (short*)(ws + O_XB);     // alias (xb dead after in_proj)
  short* ipwb   = (short*)(ws + O_IPWB);
  short* opwb   = (short*)(ws + O_OPWB);
  float* out    = (float*)d_out;
  float* wt     = out;                     // out0 region; ln_k writes last
  short* wxb    = (short*)(out + 49152);
  float* out1   = out + 2097152;

  // 0. x -> bf16 + x_skip passthrough; weight prep
  cvt_x<<<4096, 256, 0, stream>>>(x, xb, out1);
  prep_w<<<640, 256, 0, stream>>>(ipw, opw, dw, xpw, ipwb, opwb, wt, wxb);
  // 1. in_proj MFMA (32768x512, K=128) -> bf16 xcpre + bf16 silu(z)
  mgemm<512, 128, 1><<<dim3(512, 8), 256, 0, stream>>>(
      xb, ipwb, nullptr, xcpre, zact);
  // 2. depthwise causal conv + silu -> xcb (b,t,d) + xcT (b,d,t)
  conv_silu2<<<512, 256, 0, stream>>>(xcpre, cw, cb, xcb, xcT);
  // 3. x_dbl MFMA: xcb @ wxb^T (32768x64, K=256) -> fp32 xdbl
  mgemm<64, 256, 0><<<dim3(512, 1), 256, 0, stream>>>(
      xcb, wxb, xdbl, nullptr, nullptr);
  // 4. delta + z transpose -> dT, zT (b,d,t)
  repack<<<512, 256, 0, stream>>>(xdbl, zact, dtw, dtb, dT, zT);
  // 5. state-parallel scan -> yb bf16
  scan5<<<1024, 128, 0, stream>>>(xdbl, xcT, dT, zT, alog, Dp, yb);
  // 6. out_proj MFMA: h1 = y @ out_proj_w^T (32768x128, K=256), fp32 out
  mgemm<128, 256, 0><<<dim3(512, 2), 256, 0, stream>>>(
      yb, opwb, h1, nullptr, nullptr);
  // 7. fused strided down-conv -> hd (16384x128, ws)
  down_k<<<2048, 128, 0, stream>>>(h1, wt, db, hd);
  // 8. LayerNorm -> output 0 (overwrites wt/wxb staging — consumed already)
  ln_k<<<16384, 64, 0, stream>>>(hd, lng, lnb, out);
}